// Round 1
// baseline (17943.153 us; speedup 1.0000x reference)
//
#include <hip/hip_runtime.h>
#include <cstddef>

#define B_ 2
#define T_ 4096
#define NQ_ 256
#define NAUX_ 28
#define NR_ 512
#define NS_ 256
#define L_ 30

#define TM 64
#define TN 64
#define KC 16

// ---------------------------------------------------------------------------
// Embed: out[b,c,t] = causal_w[c, x[b,t], 1] + (t>0 ? causal_w[c, x[b,t-1], 0] : 0) + causal_b[c]
// causal_w layout: [NR][NQ][2]
// ---------------------------------------------------------------------------
__global__ __launch_bounds__(256) void embed_kernel(
    const int* __restrict__ x, const float* __restrict__ cw,
    const float* __restrict__ cb, float* __restrict__ out)
{
    const int tid = threadIdx.x;
    const int b = blockIdx.z;
    const int t = blockIdx.x * 64 + (tid & 63);
    const int cg = tid >> 6;              // 0..3
    const int idc = x[b * T_ + t];
    const int idp = (t > 0) ? x[b * T_ + t - 1] : -1;
    float* outB = out + (size_t)b * NR_ * T_;
    for (int c = cg; c < NR_; c += 4) {
        float v = cw[(size_t)c * (NQ_ * 2) + idc * 2 + 1] + cb[c];
        if (idp >= 0) v += cw[(size_t)c * (NQ_ * 2) + idp * 2 + 0];
        outB[(size_t)c * T_ + t] = v;
    }
}

// ---------------------------------------------------------------------------
// Gates: for layer l, compute g = sigmoid(s)*tanh(t)
// s[c,t] = sum_i W0s[c,i]*out[i,t-d] + W1s[c,i]*out[i,t] + sum_j AWs[c,j]*h[j,t] + bs[c]+abs[c]
// Wsig layout per layer: [NR][NR][2] (tap 0 = past, tap 1 = current)
// ---------------------------------------------------------------------------
__global__ __launch_bounds__(256) void gates_kernel(
    const float* __restrict__ src, const float* __restrict__ haux,
    const float* __restrict__ Wsig, const float* __restrict__ bsig,
    const float* __restrict__ Wtan, const float* __restrict__ btan,
    const float* __restrict__ AWsig, const float* __restrict__ absig,
    const float* __restrict__ AWtan, const float* __restrict__ abtan,
    float* __restrict__ g, int dil)
{
    __shared__ float sXc[KC][TN + 4];
    __shared__ float sXp[KC][TN + 4];
    __shared__ float sW0s[KC][TM + 4];
    __shared__ float sW1s[KC][TM + 4];
    __shared__ float sW0t[KC][TM + 4];
    __shared__ float sW1t[KC][TM + 4];

    const int tid = threadIdx.x;
    const int b = blockIdx.z;
    const int tBase = blockIdx.x * TN;
    const int cBase = blockIdx.y * TM;
    const int tx = tid & 15, ty = tid >> 4;

    // staging indices
    const int skk = tid >> 4;           // 0..15 (X row)
    const int stt = (tid & 15) * 4;     // 0..60 (X col)
    const int wc = tid >> 2;            // 0..63 (W row within tile)
    const int wpart = tid & 3;          // 0..3

    float acc_s[4][4] = {{0}};
    float acc_t[4][4] = {{0}};

    const float* srcB = src + (size_t)b * NR_ * T_;

    // ---- main K loop over NR input channels ----
    for (int k0 = 0; k0 < NR_; k0 += KC) {
        {
            const float* p = srcB + (size_t)(k0 + skk) * T_ + tBase + stt;
            *(float4*)&sXc[skk][stt] = *(const float4*)p;
            float vp[4];
#pragma unroll
            for (int u = 0; u < 4; u++) {
                int tp = tBase + stt + u - dil;
                vp[u] = (tp >= 0) ? p[u - dil] : 0.f;
            }
            sXp[skk][stt + 0] = vp[0];
            sXp[skk][stt + 1] = vp[1];
            sXp[skk][stt + 2] = vp[2];
            sXp[skk][stt + 3] = vp[3];
        }
        {
            const size_t rowOff = (size_t)(cBase + wc) * (NR_ * 2) + k0 * 2;
#pragma unroll
            for (int jj = 0; jj < 2; jj++) {
                int j = wpart * 2 + jj;     // float4 index 0..7 within 32-float row chunk
                float4 vs = *(const float4*)&Wsig[rowOff + j * 4];
                sW0s[j * 2 + 0][wc] = vs.x; sW1s[j * 2 + 0][wc] = vs.y;
                sW0s[j * 2 + 1][wc] = vs.z; sW1s[j * 2 + 1][wc] = vs.w;
                float4 vt = *(const float4*)&Wtan[rowOff + j * 4];
                sW0t[j * 2 + 0][wc] = vt.x; sW1t[j * 2 + 0][wc] = vt.y;
                sW0t[j * 2 + 1][wc] = vt.z; sW1t[j * 2 + 1][wc] = vt.w;
            }
        }
        __syncthreads();
#pragma unroll
        for (int kk = 0; kk < KC; kk++) {
            float4 v;
            v = *(const float4*)&sXc[kk][tx * 4]; float xc[4] = {v.x, v.y, v.z, v.w};
            v = *(const float4*)&sXp[kk][tx * 4]; float xp[4] = {v.x, v.y, v.z, v.w};
            v = *(const float4*)&sW0s[kk][ty * 4]; float w0s[4] = {v.x, v.y, v.z, v.w};
            v = *(const float4*)&sW1s[kk][ty * 4]; float w1s[4] = {v.x, v.y, v.z, v.w};
            v = *(const float4*)&sW0t[kk][ty * 4]; float w0t[4] = {v.x, v.y, v.z, v.w};
            v = *(const float4*)&sW1t[kk][ty * 4]; float w1t[4] = {v.x, v.y, v.z, v.w};
#pragma unroll
            for (int i = 0; i < 4; i++)
#pragma unroll
                for (int j = 0; j < 4; j++) {
                    acc_s[i][j] += w0s[i] * xp[j] + w1s[i] * xc[j];
                    acc_t[i][j] += w0t[i] * xp[j] + w1t[i] * xc[j];
                }
        }
        __syncthreads();
    }

    // ---- aux K loop (28 channels of h, padded to 32, only "current" tap) ----
    for (int j0 = 0; j0 < 32; j0 += KC) {
        {
            int j = j0 + skk;
            float4 v = make_float4(0.f, 0.f, 0.f, 0.f);
            if (j < NAUX_) v = *(const float4*)&haux[((size_t)b * NAUX_ + j) * T_ + tBase + stt];
            *(float4*)&sXc[skk][stt] = v;
            *(float4*)&sXp[skk][stt] = make_float4(0.f, 0.f, 0.f, 0.f);
        }
        {
#pragma unroll
            for (int u = 0; u < 4; u++) {
                int kk = wpart * 4 + u;
                int j = j0 + kk;
                float a1 = 0.f, a2 = 0.f;
                if (j < NAUX_) {
                    a1 = AWsig[(size_t)(cBase + wc) * NAUX_ + j];
                    a2 = AWtan[(size_t)(cBase + wc) * NAUX_ + j];
                }
                sW1s[kk][wc] = a1; sW0s[kk][wc] = 0.f;
                sW1t[kk][wc] = a2; sW0t[kk][wc] = 0.f;
            }
        }
        __syncthreads();
#pragma unroll
        for (int kk = 0; kk < KC; kk++) {
            float4 v;
            v = *(const float4*)&sXc[kk][tx * 4]; float xc[4] = {v.x, v.y, v.z, v.w};
            v = *(const float4*)&sXp[kk][tx * 4]; float xp[4] = {v.x, v.y, v.z, v.w};
            v = *(const float4*)&sW0s[kk][ty * 4]; float w0s[4] = {v.x, v.y, v.z, v.w};
            v = *(const float4*)&sW1s[kk][ty * 4]; float w1s[4] = {v.x, v.y, v.z, v.w};
            v = *(const float4*)&sW0t[kk][ty * 4]; float w0t[4] = {v.x, v.y, v.z, v.w};
            v = *(const float4*)&sW1t[kk][ty * 4]; float w1t[4] = {v.x, v.y, v.z, v.w};
#pragma unroll
            for (int i = 0; i < 4; i++)
#pragma unroll
                for (int j = 0; j < 4; j++) {
                    acc_s[i][j] += w0s[i] * xp[j] + w1s[i] * xc[j];
                    acc_t[i][j] += w0t[i] * xp[j] + w1t[i] * xc[j];
                }
        }
        __syncthreads();
    }

    // ---- epilogue: gating ----
    const int c0 = cBase + ty * 4, t0 = tBase + tx * 4;
    float* gB = g + (size_t)b * NR_ * T_;
#pragma unroll
    for (int i = 0; i < 4; i++) {
        float bsv = bsig[c0 + i] + absig[c0 + i];
        float btv = btan[c0 + i] + abtan[c0 + i];
        float o[4];
#pragma unroll
        for (int j = 0; j < 4; j++) {
            float sv = acc_s[i][j] + bsv;
            float tv = acc_t[i][j] + btv;
            float sg = 1.f / (1.f + __expf(-sv));
            float th = 2.f / (1.f + __expf(-2.f * tv)) - 1.f;
            o[j] = sg * th;
        }
        float4 ov = make_float4(o[0], o[1], o[2], o[3]);
        *(float4*)&gB[(size_t)(c0 + i) * T_ + t0] = ov;
    }
}

// ---------------------------------------------------------------------------
// Skip + Res: rows [0,512) -> out_new = res_w @ g + res_b + out_old
//             rows [512,768) -> skip += skip_w @ g + skip_b
// ---------------------------------------------------------------------------
__global__ __launch_bounds__(256) void skipres_kernel(
    const float* __restrict__ g, const float* __restrict__ srcOut,
    float* __restrict__ dstOut, float* __restrict__ skipAcc,
    const float* __restrict__ resW, const float* __restrict__ resB,
    const float* __restrict__ skipW, const float* __restrict__ skipB)
{
    __shared__ float sX[KC][TN + 4];
    __shared__ float sW[KC][TM + 4];

    const int tid = threadIdx.x;
    const int b = blockIdx.z;
    const int tBase = blockIdx.x * TN;
    const int cBase = blockIdx.y * TM;
    const int tx = tid & 15, ty = tid >> 4;
    const int skk = tid >> 4, stt = (tid & 15) * 4;
    const int wc = tid >> 2, wpart = tid & 3;

    const bool isRes = (cBase < NR_);
    const float* W = isRes ? (resW + (size_t)cBase * NR_)
                           : (skipW + (size_t)(cBase - NR_) * NR_);
    const float* bias = isRes ? (resB + cBase) : (skipB + (cBase - NR_));

    float acc[4][4] = {{0}};
    const float* gB = g + (size_t)b * NR_ * T_;

    for (int k0 = 0; k0 < NR_; k0 += KC) {
        *(float4*)&sX[skk][stt] = *(const float4*)&gB[(size_t)(k0 + skk) * T_ + tBase + stt];
        float4 wv = *(const float4*)&W[(size_t)wc * NR_ + k0 + wpart * 4];
        sW[wpart * 4 + 0][wc] = wv.x; sW[wpart * 4 + 1][wc] = wv.y;
        sW[wpart * 4 + 2][wc] = wv.z; sW[wpart * 4 + 3][wc] = wv.w;
        __syncthreads();
#pragma unroll
        for (int kk = 0; kk < KC; kk++) {
            float4 v = *(const float4*)&sX[kk][tx * 4]; float x[4] = {v.x, v.y, v.z, v.w};
            v = *(const float4*)&sW[kk][ty * 4]; float w[4] = {v.x, v.y, v.z, v.w};
#pragma unroll
            for (int i = 0; i < 4; i++)
#pragma unroll
                for (int j = 0; j < 4; j++)
                    acc[i][j] += w[i] * x[j];
        }
        __syncthreads();
    }

    const int c0r = ty * 4;       // row within tile
    const int t0 = tBase + tx * 4;
    if (isRes) {
        const int c0 = cBase + c0r;
        const float* sB = srcOut + (size_t)b * NR_ * T_;
        float* dB = dstOut + (size_t)b * NR_ * T_;
#pragma unroll
        for (int i = 0; i < 4; i++) {
            float bv = bias[c0r + i];
            float4 sv = *(const float4*)&sB[(size_t)(c0 + i) * T_ + t0];
            float4 ov = make_float4(acc[i][0] + bv + sv.x, acc[i][1] + bv + sv.y,
                                    acc[i][2] + bv + sv.z, acc[i][3] + bv + sv.w);
            *(float4*)&dB[(size_t)(c0 + i) * T_ + t0] = ov;
        }
    } else {
        const int c0 = cBase - NR_ + c0r;
        float* kB = skipAcc + (size_t)b * NS_ * T_;
#pragma unroll
        for (int i = 0; i < 4; i++) {
            float bv = bias[c0r + i];
            float4 old = *(const float4*)&kB[(size_t)(c0 + i) * T_ + t0];
            float4 ov = make_float4(old.x + acc[i][0] + bv, old.y + acc[i][1] + bv,
                                    old.z + acc[i][2] + bv, old.w + acc[i][3] + bv);
            *(float4*)&kB[(size_t)(c0 + i) * T_ + t0] = ov;
        }
    }
}

// ---------------------------------------------------------------------------
// Dense 1x1 conv: Y = [relu?](W @ [relu?]X + b), X/Y are (B, 256, T), W (256, Kdim)
// ---------------------------------------------------------------------------
__global__ __launch_bounds__(256) void dense_kernel(
    const float* __restrict__ X, float* __restrict__ Y,
    const float* __restrict__ W, const float* __restrict__ bias,
    int Kdim, int reluIn, int reluOut)
{
    __shared__ float sX[KC][TN + 4];
    __shared__ float sW[KC][TM + 4];

    const int tid = threadIdx.x;
    const int b = blockIdx.z;
    const int tBase = blockIdx.x * TN;
    const int cBase = blockIdx.y * TM;
    const int tx = tid & 15, ty = tid >> 4;
    const int skk = tid >> 4, stt = (tid & 15) * 4;
    const int wc = tid >> 2, wpart = tid & 3;

    float acc[4][4] = {{0}};
    const float* xB = X + (size_t)b * Kdim * T_;

    for (int k0 = 0; k0 < Kdim; k0 += KC) {
        float4 xv = *(const float4*)&xB[(size_t)(k0 + skk) * T_ + tBase + stt];
        if (reluIn) {
            xv.x = fmaxf(xv.x, 0.f); xv.y = fmaxf(xv.y, 0.f);
            xv.z = fmaxf(xv.z, 0.f); xv.w = fmaxf(xv.w, 0.f);
        }
        *(float4*)&sX[skk][stt] = xv;
        float4 wv = *(const float4*)&W[(size_t)(cBase + wc) * Kdim + k0 + wpart * 4];
        sW[wpart * 4 + 0][wc] = wv.x; sW[wpart * 4 + 1][wc] = wv.y;
        sW[wpart * 4 + 2][wc] = wv.z; sW[wpart * 4 + 3][wc] = wv.w;
        __syncthreads();
#pragma unroll
        for (int kk = 0; kk < KC; kk++) {
            float4 v = *(const float4*)&sX[kk][tx * 4]; float x[4] = {v.x, v.y, v.z, v.w};
            v = *(const float4*)&sW[kk][ty * 4]; float w[4] = {v.x, v.y, v.z, v.w};
#pragma unroll
            for (int i = 0; i < 4; i++)
#pragma unroll
                for (int j = 0; j < 4; j++)
                    acc[i][j] += w[i] * x[j];
        }
        __syncthreads();
    }

    const int c0 = cBase + ty * 4, t0 = tBase + tx * 4;
    float* yB = Y + (size_t)b * NS_ * T_;
#pragma unroll
    for (int i = 0; i < 4; i++) {
        float bv = bias[c0 + i];
        float o[4];
#pragma unroll
        for (int j = 0; j < 4; j++) {
            float v = acc[i][j] + bv;
            o[j] = reluOut ? fmaxf(v, 0.f) : v;
        }
        *(float4*)&yB[(size_t)(c0 + i) * T_ + t0] = make_float4(o[0], o[1], o[2], o[3]);
    }
}

// ---------------------------------------------------------------------------
// Final: out[b,t,q] = sum_j lin_w[q,j] * X[b,j,t] + lin_b[q]   (output is (B,T,NQ))
// ---------------------------------------------------------------------------
__global__ __launch_bounds__(256) void final_kernel(
    const float* __restrict__ X, float* __restrict__ out,
    const float* __restrict__ W, const float* __restrict__ bias)
{
    __shared__ float sX[KC][TN + 4];
    __shared__ float sW[KC][TM + 4];

    const int tid = threadIdx.x;
    const int b = blockIdx.z;
    const int tBase = blockIdx.x * TN;
    const int cBase = blockIdx.y * TM;   // q
    const int tx = tid & 15, ty = tid >> 4;
    const int skk = tid >> 4, stt = (tid & 15) * 4;
    const int wc = tid >> 2, wpart = tid & 3;

    float acc[4][4] = {{0}};
    const float* xB = X + (size_t)b * NQ_ * T_;

    for (int k0 = 0; k0 < NQ_; k0 += KC) {
        *(float4*)&sX[skk][stt] = *(const float4*)&xB[(size_t)(k0 + skk) * T_ + tBase + stt];
        float4 wv = *(const float4*)&W[(size_t)(cBase + wc) * NQ_ + k0 + wpart * 4];
        sW[wpart * 4 + 0][wc] = wv.x; sW[wpart * 4 + 1][wc] = wv.y;
        sW[wpart * 4 + 2][wc] = wv.z; sW[wpart * 4 + 3][wc] = wv.w;
        __syncthreads();
#pragma unroll
        for (int kk = 0; kk < KC; kk++) {
            float4 v = *(const float4*)&sX[kk][tx * 4]; float x[4] = {v.x, v.y, v.z, v.w};
            v = *(const float4*)&sW[kk][ty * 4]; float w[4] = {v.x, v.y, v.z, v.w};
#pragma unroll
            for (int i = 0; i < 4; i++)
#pragma unroll
                for (int j = 0; j < 4; j++)
                    acc[i][j] += w[i] * x[j];
        }
        __syncthreads();
    }

    const int c0 = cBase + ty * 4, t0 = tBase + tx * 4;
#pragma unroll
    for (int i = 0; i < 4; i++) {
        float bv = bias[c0 + i];
#pragma unroll
        for (int j = 0; j < 4; j++) {
            out[((size_t)b * T_ + t0 + j) * NQ_ + c0 + i] = acc[i][j] + bv;
        }
    }
}

// ---------------------------------------------------------------------------
extern "C" void kernel_launch(void* const* d_in, const int* in_sizes, int n_in,
                              void* d_out, int out_size, void* d_ws, size_t ws_size,
                              hipStream_t stream)
{
    (void)in_sizes; (void)n_in; (void)out_size; (void)ws_size;

    const int* x = (const int*)d_in[0];
    const float* h = (const float*)d_in[1];
    const float* causal_w = (const float*)d_in[2];
    const float* causal_b = (const float*)d_in[3];
    const float* dsw = (const float*)d_in[4];
    const float* dsb = (const float*)d_in[5];
    const float* dtw = (const float*)d_in[6];
    const float* dtb = (const float*)d_in[7];
    const float* asw = (const float*)d_in[8];
    const float* asb = (const float*)d_in[9];
    const float* atw = (const float*)d_in[10];
    const float* atb = (const float*)d_in[11];
    const float* skw = (const float*)d_in[12];
    const float* skb = (const float*)d_in[13];
    const float* rsw = (const float*)d_in[14];
    const float* rsb = (const float*)d_in[15];
    const float* p1w = (const float*)d_in[16];
    const float* p1b = (const float*)d_in[17];
    const float* p2w = (const float*)d_in[18];
    const float* p2b = (const float*)d_in[19];
    const float* lw  = (const float*)d_in[20];
    const float* lb  = (const float*)d_in[21];
    float* out = (float*)d_out;

    float* bufA  = (float*)d_ws;
    float* bufB  = bufA + (size_t)B_ * NR_ * T_;
    float* gbuf  = bufB + (size_t)B_ * NR_ * T_;
    float* skipb = gbuf + (size_t)B_ * NR_ * T_;

    hipMemsetAsync(skipb, 0, (size_t)B_ * NS_ * T_ * sizeof(float), stream);

    embed_kernel<<<dim3(T_ / 64, 1, B_), 256, 0, stream>>>(x, causal_w, causal_b, bufA);

    float* cur = bufA;
    float* nxt = bufB;
    for (int l = 0; l < L_; l++) {
        const int dil = 1 << (l % 10);
        gates_kernel<<<dim3(T_ / TN, NR_ / TM, B_), 256, 0, stream>>>(
            cur, h,
            dsw + (size_t)l * NR_ * NR_ * 2, dsb + (size_t)l * NR_,
            dtw + (size_t)l * NR_ * NR_ * 2, dtb + (size_t)l * NR_,
            asw + (size_t)l * NR_ * NAUX_, asb + (size_t)l * NR_,
            atw + (size_t)l * NR_ * NAUX_, atb + (size_t)l * NR_,
            gbuf, dil);
        skipres_kernel<<<dim3(T_ / TN, (NR_ + NS_) / TM, B_), 256, 0, stream>>>(
            gbuf, cur, nxt, skipb,
            rsw + (size_t)l * NR_ * NR_, rsb + (size_t)l * NR_,
            skw + (size_t)l * NS_ * NR_, skb + (size_t)l * NS_);
        float* tmp = cur; cur = nxt; nxt = tmp;
    }

    // post: o2 = relu(p1w @ relu(skip) + p1b) -> gbuf
    dense_kernel<<<dim3(T_ / TN, NS_ / TM, B_), 256, 0, stream>>>(
        skipb, gbuf, p1w, p1b, NS_, 1, 1);
    // o3 = p2w @ o2 + p2b -> bufB
    dense_kernel<<<dim3(T_ / TN, NQ_ / TM, B_), 256, 0, stream>>>(
        gbuf, bufB, p2w, p2b, NS_, 0, 0);
    // out[b,t,q] = lin_w @ o3 + lin_b
    final_kernel<<<dim3(T_ / TN, NQ_ / TM, B_), 256, 0, stream>>>(
        bufB, out, lw, lb);
}

// Round 3
// 2607.236 us; speedup vs baseline: 6.8821x; 6.8821x over previous
//
#include <hip/hip_runtime.h>
#include <cstddef>

#define B_ 2
#define T_ 4096
#define NQ_ 256
#define NAUX_ 28
#define NR_ 512
#define NS_ 256
#define L_ 30

#define LDSPAD 72   // fp16 elements per LDS tile row (64 data + 8 pad; 144 B, bank-balanced)

typedef _Float16 half_t;
typedef __attribute__((ext_vector_type(8))) _Float16 f16x8;
typedef __attribute__((ext_vector_type(4))) _Float16 f16x4;
typedef __attribute__((ext_vector_type(4))) float f32x4;

__device__ inline half_t f2h(float f) { return (half_t)f; }
__device__ inline float h2f(half_t h) { return (float)h; }

// ---------------------------------------------------------------------------
// Generic fp16 MFMA GEMM: out[b][t][m] = sum_k W[m][k] * X[b][t][k] (+bias[m])
// X: [B][4096][K] fp16 (K % 64 == 0), W: [M][K] fp16, grid (32, M/128, B)
// EPI: 0 = fp16 store, 1 = fp16+relu, 2 = f32 store
// ---------------------------------------------------------------------------
template<int EPI>
__global__ __launch_bounds__(256) void gemm_mfma(
    const half_t* __restrict__ X, const half_t* __restrict__ W,
    const float* __restrict__ bias, void* __restrict__ out, int M, int K)
{
    __shared__ __align__(16) half_t sA[128 * LDSPAD];  // W tile
    __shared__ __align__(16) half_t sB[128 * LDSPAD];  // X tile

    const int tid = threadIdx.x;
    const int b = blockIdx.z;
    const int tB = blockIdx.x * 128;
    const int mB = blockIdx.y * 128;
    const int wid = tid >> 6, lane = tid & 63;
    const int wm = wid >> 1, wn = wid & 1;
    const int l15 = lane & 15, lg = lane >> 4;

    f32x4 acc[4][4] = {};

    const half_t* Xb = X + ((size_t)b * T_ + tB) * K;
    const half_t* Wb = W + (size_t)mB * K;

    const int sc = tid & 7, sr = tid >> 3;   // staging: 8 chunks x 32 rows

    const int nk = K >> 6;
    for (int kc = 0; kc < nk; kc++) {
        const int k0 = kc << 6;
#pragma unroll
        for (int it = 0; it < 4; it++) {
            const int r = sr + it * 32;
            *(uint4*)&sA[r * LDSPAD + sc * 8] = *(const uint4*)&Wb[(size_t)r * K + k0 + sc * 8];
            *(uint4*)&sB[r * LDSPAD + sc * 8] = *(const uint4*)&Xb[(size_t)r * K + k0 + sc * 8];
        }
        __syncthreads();
#pragma unroll
        for (int s = 0; s < 2; s++) {
            f16x8 av[4], bv[4];
#pragma unroll
            for (int i = 0; i < 4; i++)
                av[i] = *(const f16x8*)&sA[(wm * 64 + i * 16 + l15) * LDSPAD + s * 32 + lg * 8];
#pragma unroll
            for (int j = 0; j < 4; j++)
                bv[j] = *(const f16x8*)&sB[(wn * 64 + j * 16 + l15) * LDSPAD + s * 32 + lg * 8];
#pragma unroll
            for (int i = 0; i < 4; i++)
#pragma unroll
                for (int j = 0; j < 4; j++)
                    acc[i][j] = __builtin_amdgcn_mfma_f32_16x16x32_f16(av[i], bv[j], acc[i][j], 0, 0, 0);
        }
        __syncthreads();
    }

    const int n0 = tB + wn * 64 + l15;
#pragma unroll
    for (int i = 0; i < 4; i++) {
        const int m = mB + wm * 64 + i * 16 + lg * 4;
        float4 bv = make_float4(0.f, 0.f, 0.f, 0.f);
        if (bias) bv = *(const float4*)&bias[m];
#pragma unroll
        for (int j = 0; j < 4; j++) {
            const int t = n0 + j * 16;
            float o0 = acc[i][j][0] + bv.x, o1 = acc[i][j][1] + bv.y;
            float o2 = acc[i][j][2] + bv.z, o3 = acc[i][j][3] + bv.w;
            if (EPI == 1) {
                o0 = fmaxf(o0, 0.f); o1 = fmaxf(o1, 0.f);
                o2 = fmaxf(o2, 0.f); o3 = fmaxf(o3, 0.f);
            }
            const size_t off = ((size_t)b * T_ + t) * M + m;
            if (EPI == 2) {
                *(float4*)((float*)out + off) = make_float4(o0, o1, o2, o3);
            } else {
                f16x4 ov = {f2h(o0), f2h(o1), f2h(o2), f2h(o3)};
                *(f16x4*)((half_t*)out + off) = ov;
            }
        }
    }
}

// ---------------------------------------------------------------------------
// Gating: g[t][c] = sigmoid(Z[t][c] + Z[t-d][512+c]) * tanh(Z[t][1024+c] + Z[t-d][1536+c])
// ---------------------------------------------------------------------------
__global__ __launch_bounds__(256) void gating_kernel(
    const half_t* __restrict__ Z, half_t* __restrict__ g, int dil)
{
    const int idx = blockIdx.x * 256 + threadIdx.x;     // B*4096*128
    const int c = (idx & 127) * 4;
    const int t = (idx >> 7) & 4095;
    const int b = idx >> 19;
    const size_t base = ((size_t)(b * T_ + t)) * 2048;
    const f16x4 zs = *(const f16x4*)(Z + base + c);
    const f16x4 zt = *(const f16x4*)(Z + base + 1024 + c);
    float sv[4] = {h2f(zs.x), h2f(zs.y), h2f(zs.z), h2f(zs.w)};
    float tv[4] = {h2f(zt.x), h2f(zt.y), h2f(zt.z), h2f(zt.w)};
    const int tp = t - dil;
    if (tp >= 0) {
        const size_t bp = ((size_t)(b * T_ + tp)) * 2048;
        const f16x4 ps = *(const f16x4*)(Z + bp + 512 + c);
        const f16x4 pt = *(const f16x4*)(Z + bp + 1536 + c);
        sv[0] += h2f(ps.x); sv[1] += h2f(ps.y); sv[2] += h2f(ps.z); sv[3] += h2f(ps.w);
        tv[0] += h2f(pt.x); tv[1] += h2f(pt.y); tv[2] += h2f(pt.z); tv[3] += h2f(pt.w);
    }
    f16x4 o;
#pragma unroll
    for (int e = 0; e < 4; e++) {
        const float sg = 1.f / (1.f + __expf(-sv[e]));
        const float ex = __expf(-2.f * tv[e]);
        const float th = (1.f - ex) / (1.f + ex);
        o[e] = f2h(sg * th);
    }
    *(f16x4*)(g + ((size_t)(b * T_ + t)) * 512 + c) = o;
}

// ---------------------------------------------------------------------------
// Residual + skip epilogue. P[t][0..512) = res delta (bias included),
// P[t][512..768) = skip delta (bias included).
// ---------------------------------------------------------------------------
__global__ __launch_bounds__(256) void resskip_kernel(
    const half_t* __restrict__ P, float* __restrict__ actF,
    half_t* __restrict__ actB, float* __restrict__ skipAcc)
{
    const int idx = blockIdx.x * 256 + threadIdx.x;     // 8192*192
    const int c4 = idx % 192;
    const int bt = idx / 192;
    const f16x4 p4 = *(const f16x4*)(P + (size_t)bt * 768 + c4 * 4);
    if (c4 < 128) {
        const int c = c4 * 4;
        float4 old = *(float4*)(actF + (size_t)bt * 512 + c);
        const float4 nv = make_float4(old.x + h2f(p4.x), old.y + h2f(p4.y),
                                      old.z + h2f(p4.z), old.w + h2f(p4.w));
        *(float4*)(actF + (size_t)bt * 512 + c) = nv;
        f16x4 m = {f2h(nv.x), f2h(nv.y), f2h(nv.z), f2h(nv.w)};
        *(f16x4*)(actB + (size_t)bt * 576 + c) = m;
    } else {
        const int c = (c4 - 128) * 4;
        float* sp = skipAcc + (size_t)bt * 256 + c;
        float4 s = *(float4*)sp;
        s.x += h2f(p4.x); s.y += h2f(p4.y); s.z += h2f(p4.z); s.w += h2f(p4.w);
        *(float4*)sp = s;
    }
}

// relu(skipAcc) -> fp16
__global__ __launch_bounds__(256) void relupack_kernel(
    const float* __restrict__ skipAcc, half_t* __restrict__ outp)
{
    const int idx = blockIdx.x * 256 + threadIdx.x;     // 8192*64
    const int c = (idx & 63) * 4;
    const int bt = idx >> 6;
    const float4 v = *(const float4*)(skipAcc + (size_t)bt * 256 + c);
    f16x4 o = {f2h(fmaxf(v.x, 0.f)), f2h(fmaxf(v.y, 0.f)),
               f2h(fmaxf(v.z, 0.f)), f2h(fmaxf(v.w, 0.f))};
    *(f16x4*)(outp + (size_t)bt * 256 + c) = o;
}

// ---------------------------------------------------------------------------
// Embed: actF[t][c] = cw[c][x[t]][1] + cw[c][x[t-1]][0] + cb[c]; fp16 mirror too
// ---------------------------------------------------------------------------
__global__ __launch_bounds__(256) void embed_kernel(
    const int* __restrict__ x, const float* __restrict__ cw,
    const float* __restrict__ cb, float* __restrict__ actF, half_t* __restrict__ actB)
{
    const int t = blockIdx.x, b = blockIdx.y;
    const int idc = x[b * T_ + t];
    const int idp = (t > 0) ? x[b * T_ + t - 1] : -1;
    const size_t bt = (size_t)b * T_ + t;
    for (int c = threadIdx.x; c < 512; c += 256) {
        float v = cw[(c * 256 + idc) * 2 + 1] + cb[c];
        if (idp >= 0) v += cw[(c * 256 + idp) * 2 + 0];
        actF[bt * 512 + c] = v;
        actB[bt * 576 + c] = f2h(v);
    }
}

// aux channels of X: actB[t][512+j] = fp16(h[b][j][t]) for j<28 else 0
__global__ __launch_bounds__(256) void packh_kernel(
    const float* __restrict__ h, half_t* __restrict__ actB)
{
    const int idx = blockIdx.x * 256 + threadIdx.x;     // 8192*64
    const int j = idx & 63;
    const int bt = idx >> 6;
    const int b = bt >> 12, t = bt & 4095;
    const float v = (j < 28) ? h[((size_t)b * NAUX_ + j) * T_ + t] : 0.f;
    actB[(size_t)bt * 576 + 512 + j] = f2h(v);
}

// ---------------------------------------------------------------------------
// Weight packing
// ---------------------------------------------------------------------------
__device__ inline float wall_src(const float* dsw, const float* dtw,
                                 const float* asw, const float* atw,
                                 int l, int r, int c)
{
    const int rr = r & 511;
    if (r < 1024) {
        if (c < 512) return dsw[(((size_t)l * 512 + rr) * 512 + c) * 2 + (r < 512 ? 1 : 0)];
        if (r < 512 && c < 540) return asw[((size_t)l * 512 + rr) * NAUX_ + (c - 512)];
        return 0.f;
    } else {
        if (c < 512) return dtw[(((size_t)l * 512 + rr) * 512 + c) * 2 + (r < 1536 ? 1 : 0)];
        if (r < 1536 && c < 540) return atw[((size_t)l * 512 + rr) * NAUX_ + (c - 512)];
        return 0.f;
    }
}

__global__ __launch_bounds__(256) void packwall_kernel(
    const float* __restrict__ dsw, const float* __restrict__ dtw,
    const float* __restrict__ asw, const float* __restrict__ atw,
    half_t* __restrict__ Wall)
{
    const int idx = blockIdx.x * 256 + threadIdx.x;     // 30*2048*144
    const int c = (idx % 144) * 4;
    const int r = (idx / 144) & 2047;
    const int l = idx / (144 * 2048);
    f16x4 o;
#pragma unroll
    for (int e = 0; e < 4; e++)
        o[e] = f2h(wall_src(dsw, dtw, asw, atw, l, r, c + e));
    *(f16x4*)(Wall + ((size_t)l * 2048 + r) * 576 + c) = o;
}

__global__ __launch_bounds__(256) void packsr_kernel(
    const float* __restrict__ rsw, const float* __restrict__ skw,
    half_t* __restrict__ Wsr)
{
    const int idx = blockIdx.x * 256 + threadIdx.x;     // 30*768*128
    const int c = (idx & 127) * 4;
    const int r = (idx >> 7) % 768;
    const int l = idx / (128 * 768);
    const float4 v = (r < 512)
        ? *(const float4*)&rsw[((size_t)l * 512 + r) * 512 + c]
        : *(const float4*)&skw[((size_t)l * 256 + (r - 512)) * 512 + c];
    f16x4 o = {f2h(v.x), f2h(v.y), f2h(v.z), f2h(v.w)};
    *(f16x4*)(Wsr + ((size_t)l * 768 + r) * 512 + c) = o;
}

__global__ __launch_bounds__(256) void packpost_kernel(
    const float* __restrict__ p1w, const float* __restrict__ p2w,
    const float* __restrict__ lw, half_t* __restrict__ Wpost)
{
    const int idx = blockIdx.x * 256 + threadIdx.x;     // 3*256*64
    const int c = (idx & 63) * 4;
    const int r = (idx >> 6) & 255;
    const int mi = idx >> 14;
    const float* src = (mi == 0) ? p1w : (mi == 1) ? p2w : lw;
    const float4 v = *(const float4*)&src[(size_t)r * 256 + c];
    f16x4 o = {f2h(v.x), f2h(v.y), f2h(v.z), f2h(v.w)};
    *(f16x4*)(Wpost + (size_t)mi * 65536 + (size_t)r * 256 + c) = o;
}

__global__ __launch_bounds__(256) void packbias_kernel(
    const float* __restrict__ dsb, const float* __restrict__ asb,
    const float* __restrict__ dtb, const float* __restrict__ atb,
    const float* __restrict__ rsb, const float* __restrict__ skb,
    float* __restrict__ biasAll, float* __restrict__ biasSr)
{
    const int idx = blockIdx.x * 256 + threadIdx.x;
    if (idx < 30 * 2048) {
        const int l = idx >> 11, r = idx & 2047;
        float v = 0.f;
        if (r < 512) v = dsb[l * 512 + r] + asb[l * 512 + r];
        else if (r >= 1024 && r < 1536) v = dtb[l * 512 + (r - 1024)] + atb[l * 512 + (r - 1024)];
        biasAll[idx] = v;
    } else if (idx < 30 * 2048 + 30 * 768) {
        const int j = idx - 30 * 2048;
        const int l = j / 768, r = j % 768;
        biasSr[j] = (r < 512) ? rsb[l * 512 + r] : skb[l * 256 + (r - 512)];
    }
}

// ---------------------------------------------------------------------------
extern "C" void kernel_launch(void* const* d_in, const int* in_sizes, int n_in,
                              void* d_out, int out_size, void* d_ws, size_t ws_size,
                              hipStream_t stream)
{
    (void)in_sizes; (void)n_in; (void)out_size; (void)ws_size;

    const int* x = (const int*)d_in[0];
    const float* h = (const float*)d_in[1];
    const float* causal_w = (const float*)d_in[2];
    const float* causal_b = (const float*)d_in[3];
    const float* dsw = (const float*)d_in[4];
    const float* dsb = (const float*)d_in[5];
    const float* dtw = (const float*)d_in[6];
    const float* dtb = (const float*)d_in[7];
    const float* asw = (const float*)d_in[8];
    const float* asb = (const float*)d_in[9];
    const float* atw = (const float*)d_in[10];
    const float* atb = (const float*)d_in[11];
    const float* skw = (const float*)d_in[12];
    const float* skb = (const float*)d_in[13];
    const float* rsw = (const float*)d_in[14];
    const float* rsb = (const float*)d_in[15];
    const float* p1w = (const float*)d_in[16];
    const float* p1b = (const float*)d_in[17];
    const float* p2w = (const float*)d_in[18];
    const float* p2b = (const float*)d_in[19];
    const float* lw  = (const float*)d_in[20];
    const float* lb  = (const float*)d_in[21];

    char* ws = (char*)d_ws;
    size_t off = 0;
    auto alloc = [&](size_t bytes) { char* p = ws + off; off += (bytes + 255) & ~(size_t)255; return p; };

    half_t* Wall   = (half_t*)alloc((size_t)L_ * 2048 * 576 * 2);
    half_t* Wsr    = (half_t*)alloc((size_t)L_ * 768 * 512 * 2);
    half_t* Wpost  = (half_t*)alloc((size_t)3 * 256 * 256 * 2);
    float*  biasAll= (float*) alloc((size_t)L_ * 2048 * 4);
    float*  biasSr = (float*) alloc((size_t)L_ * 768 * 4);
    float*  actF   = (float*) alloc((size_t)B_ * T_ * 512 * 4);
    half_t* actB   = (half_t*)alloc((size_t)B_ * T_ * 576 * 2);
    half_t* Z      = (half_t*)alloc((size_t)B_ * T_ * 2048 * 2);
    half_t* g      = (half_t*)alloc((size_t)B_ * T_ * 512 * 2);
    half_t* P      = (half_t*)alloc((size_t)B_ * T_ * 768 * 2);
    float*  skipAcc= (float*) alloc((size_t)B_ * T_ * 256 * 4);
    half_t* pA     = (half_t*)alloc((size_t)B_ * T_ * 256 * 2);
    half_t* pB     = (half_t*)alloc((size_t)B_ * T_ * 256 * 2);

    hipMemsetAsync(skipAcc, 0, (size_t)B_ * T_ * 256 * 4, stream);

    packwall_kernel<<<30 * 2048 * 144 / 256, 256, 0, stream>>>(dsw, dtw, asw, atw, Wall);
    packsr_kernel<<<30 * 768 * 128 / 256, 256, 0, stream>>>(rsw, skw, Wsr);
    packpost_kernel<<<3 * 256 * 64 / 256, 256, 0, stream>>>(p1w, p2w, lw, Wpost);
    packbias_kernel<<<(30 * 2048 + 30 * 768 + 255) / 256, 256, 0, stream>>>(
        dsb, asb, dtb, atb, rsb, skb, biasAll, biasSr);
    packh_kernel<<<B_ * T_ * 64 / 256, 256, 0, stream>>>(h, actB);
    embed_kernel<<<dim3(T_, B_), 256, 0, stream>>>(x, causal_w, causal_b, actF, actB);

    for (int l = 0; l < L_; l++) {
        const int dil = 1 << (l % 10);
        gemm_mfma<0><<<dim3(32, 16, B_), 256, 0, stream>>>(
            actB, Wall + (size_t)l * 2048 * 576, biasAll + (size_t)l * 2048, Z, 2048, 576);
        gating_kernel<<<B_ * T_ * 128 / 256, 256, 0, stream>>>(Z, g, dil);
        gemm_mfma<0><<<dim3(32, 6, B_), 256, 0, stream>>>(
            g, Wsr + (size_t)l * 768 * 512, biasSr + (size_t)l * 768, P, 768, 512);
        resskip_kernel<<<B_ * T_ * 192 / 256, 256, 0, stream>>>(P, actF, actB, skipAcc);
    }

    relupack_kernel<<<B_ * T_ * 64 / 256, 256, 0, stream>>>(skipAcc, pA);
    gemm_mfma<1><<<dim3(32, 2, B_), 256, 0, stream>>>(pA, Wpost, p1b, pB, 256, 256);
    gemm_mfma<0><<<dim3(32, 2, B_), 256, 0, stream>>>(pB, Wpost + 65536, p2b, pA, 256, 256);
    gemm_mfma<2><<<dim3(32, 2, B_), 256, 0, stream>>>(pA, Wpost + 131072, lb, d_out, 256, 256);
}

// Round 4
// 2367.835 us; speedup vs baseline: 7.5779x; 1.1011x over previous
//
#include <hip/hip_runtime.h>
#include <cstddef>

#define B_ 2
#define T_ 4096
#define NQ_ 256
#define NAUX_ 28
#define NR_ 512
#define NS_ 256
#define L_ 30

typedef _Float16 half_t;
typedef __attribute__((ext_vector_type(8))) _Float16 f16x8;
typedef __attribute__((ext_vector_type(4))) _Float16 f16x4;
typedef __attribute__((ext_vector_type(4))) float f32x4;

__device__ inline half_t f2h(float f) { return (half_t)f; }
__device__ inline float h2f(half_t h) { return (float)h; }

// async global->LDS, 16 B per lane; LDS dest = base + lane*16 (wave-uniform base)
__device__ __forceinline__ void gload16(const void* g, void* l) {
    __builtin_amdgcn_global_load_lds(
        (const __attribute__((address_space(1))) unsigned int*)g,
        (__attribute__((address_space(3))) unsigned int*)l, 16, 0, 0);
}

// ---------------------------------------------------------------------------
// fp16 MFMA GEMM v2: out[b][t][m] = sum_k W[m][k] * X[b][t][k] (+bias[m])
// X: [B][4096][K] fp16 (K%64==0), W: [M][K] fp16, grid (32, M/128, B), 256 thr.
// LDS tiles 128x64 fp16 unpadded; staged by global_load_lds with XOR chunk
// swizzle: LDS[row][chunk c] holds global chunk c^(row&7)  (bank-conflict-free
// ds_read_b128: lanes cover all 32 banks at 2 lanes/bank).
// EPI: 0 = fp16 store, 1 = fp16+relu, 2 = f32 store,
//      3 = fused res/skip (m<512: actF+=, mirror to actB; m>=512: skipAcc+=)
// ---------------------------------------------------------------------------
template<int EPI>
__global__ __launch_bounds__(256) void gemm_mfma(
    const half_t* __restrict__ X, const half_t* __restrict__ W,
    const float* __restrict__ bias, void* __restrict__ out, int M, int K,
    float* __restrict__ actF, half_t* __restrict__ actB,
    float* __restrict__ skipAcc)
{
    __shared__ __align__(16) half_t sA[128 * 64];  // W tile
    __shared__ __align__(16) half_t sB[128 * 64];  // X tile

    const int tid = threadIdx.x;
    const int b = blockIdx.z;
    const int tB = blockIdx.x * 128;
    const int mB = blockIdx.y * 128;
    const int w = tid >> 6, lane = tid & 63;
    const int wm = w >> 1, wn = w & 1;
    const int l15 = lane & 15, lg = lane >> 4;
    const int rr = lane >> 3, cc = lane & 7;
    const int sc8 = cc ^ rr;               // swizzled global chunk for staging

    f32x4 acc[4][4] = {};

    const half_t* Xb = X + ((size_t)b * T_ + tB) * K;
    const half_t* Wb = W + (size_t)mB * K;

    const int nk = K >> 6;
    for (int kc = 0; kc < nk; kc++) {
        const int k0 = kc << 6;
#pragma unroll
        for (int it = 0; it < 4; it++) {
            const int row = w * 32 + it * 8 + rr;
            gload16(Wb + (size_t)row * K + k0 + sc8 * 8, &sA[(w * 32 + it * 8) * 64]);
            gload16(Xb + (size_t)row * K + k0 + sc8 * 8, &sB[(w * 32 + it * 8) * 64]);
        }
        __syncthreads();
#pragma unroll
        for (int s = 0; s < 2; s++) {
            f16x8 av[4], bv[4];
#pragma unroll
            for (int i = 0; i < 4; i++) {
                const int r = wm * 64 + i * 16 + l15;
                av[i] = *(const f16x8*)&sA[r * 64 + (((s * 4 + lg) ^ (l15 & 7)) * 8)];
            }
#pragma unroll
            for (int j = 0; j < 4; j++) {
                const int r = wn * 64 + j * 16 + l15;
                bv[j] = *(const f16x8*)&sB[r * 64 + (((s * 4 + lg) ^ (l15 & 7)) * 8)];
            }
#pragma unroll
            for (int i = 0; i < 4; i++)
#pragma unroll
                for (int j = 0; j < 4; j++)
                    acc[i][j] = __builtin_amdgcn_mfma_f32_16x16x32_f16(av[i], bv[j], acc[i][j], 0, 0, 0);
        }
        __syncthreads();
    }

    const int n0 = tB + wn * 64 + l15;
#pragma unroll
    for (int i = 0; i < 4; i++) {
        const int m = mB + wm * 64 + i * 16 + lg * 4;
        float4 bv = make_float4(0.f, 0.f, 0.f, 0.f);
        if (bias) bv = *(const float4*)&bias[m];
#pragma unroll
        for (int j = 0; j < 4; j++) {
            const int t = n0 + j * 16;
            float o0 = acc[i][j][0] + bv.x, o1 = acc[i][j][1] + bv.y;
            float o2 = acc[i][j][2] + bv.z, o3 = acc[i][j][3] + bv.w;
            if (EPI == 1) {
                o0 = fmaxf(o0, 0.f); o1 = fmaxf(o1, 0.f);
                o2 = fmaxf(o2, 0.f); o3 = fmaxf(o3, 0.f);
            }
            if (EPI == 3) {
                const size_t bt = (size_t)b * T_ + t;
                if (mB < 512) {           // residual rows
                    const size_t o = bt * 512 + m;
                    float4 old = *(float4*)(actF + o);
                    const float4 nv = make_float4(old.x + o0, old.y + o1,
                                                  old.z + o2, old.w + o3);
                    *(float4*)(actF + o) = nv;
                    f16x4 mr = {f2h(nv.x), f2h(nv.y), f2h(nv.z), f2h(nv.w)};
                    *(f16x4*)(actB + bt * 576 + m) = mr;
                } else {                  // skip rows
                    const size_t o = bt * 256 + (m - 512);
                    float4 s4 = *(float4*)(skipAcc + o);
                    s4.x += o0; s4.y += o1; s4.z += o2; s4.w += o3;
                    *(float4*)(skipAcc + o) = s4;
                }
            } else {
                const size_t off = ((size_t)b * T_ + t) * M + m;
                if (EPI == 2) {
                    *(float4*)((float*)out + off) = make_float4(o0, o1, o2, o3);
                } else {
                    f16x4 ov = {f2h(o0), f2h(o1), f2h(o2), f2h(o3)};
                    *(f16x4*)((half_t*)out + off) = ov;
                }
            }
        }
    }
}

// ---------------------------------------------------------------------------
// Gating: g[t][c] = sigmoid(Z[t][c] + Z[t-d][512+c]) * tanh(Z[t][1024+c] + Z[t-d][1536+c])
// ---------------------------------------------------------------------------
__global__ __launch_bounds__(256) void gating_kernel(
    const half_t* __restrict__ Z, half_t* __restrict__ g, int dil)
{
    const int idx = blockIdx.x * 256 + threadIdx.x;     // B*4096*128
    const int c = (idx & 127) * 4;
    const int t = (idx >> 7) & 4095;
    const int b = idx >> 19;
    const size_t base = ((size_t)(b * T_ + t)) * 2048;
    const f16x4 zs = *(const f16x4*)(Z + base + c);
    const f16x4 zt = *(const f16x4*)(Z + base + 1024 + c);
    float sv[4] = {h2f(zs.x), h2f(zs.y), h2f(zs.z), h2f(zs.w)};
    float tv[4] = {h2f(zt.x), h2f(zt.y), h2f(zt.z), h2f(zt.w)};
    const int tp = t - dil;
    if (tp >= 0) {
        const size_t bp = ((size_t)(b * T_ + tp)) * 2048;
        const f16x4 ps = *(const f16x4*)(Z + bp + 512 + c);
        const f16x4 pt = *(const f16x4*)(Z + bp + 1536 + c);
        sv[0] += h2f(ps.x); sv[1] += h2f(ps.y); sv[2] += h2f(ps.z); sv[3] += h2f(ps.w);
        tv[0] += h2f(pt.x); tv[1] += h2f(pt.y); tv[2] += h2f(pt.z); tv[3] += h2f(pt.w);
    }
    f16x4 o;
#pragma unroll
    for (int e = 0; e < 4; e++) {
        const float sg = 1.f / (1.f + __expf(-sv[e]));
        const float ex = __expf(-2.f * tv[e]);
        const float th = (1.f - ex) / (1.f + ex);
        o[e] = f2h(sg * th);
    }
    *(f16x4*)(g + ((size_t)(b * T_ + t)) * 512 + c) = o;
}

// relu(skipAcc) -> fp16
__global__ __launch_bounds__(256) void relupack_kernel(
    const float* __restrict__ skipAcc, half_t* __restrict__ outp)
{
    const int idx = blockIdx.x * 256 + threadIdx.x;     // 8192*64
    const int c = (idx & 63) * 4;
    const int bt = idx >> 6;
    const float4 v = *(const float4*)(skipAcc + (size_t)bt * 256 + c);
    f16x4 o = {f2h(fmaxf(v.x, 0.f)), f2h(fmaxf(v.y, 0.f)),
               f2h(fmaxf(v.z, 0.f)), f2h(fmaxf(v.w, 0.f))};
    *(f16x4*)(outp + (size_t)bt * 256 + c) = o;
}

// ---------------------------------------------------------------------------
// Embed: actF[t][c] = cw[c][x[t]][1] + cw[c][x[t-1]][0] + cb[c]; fp16 mirror too
// ---------------------------------------------------------------------------
__global__ __launch_bounds__(256) void embed_kernel(
    const int* __restrict__ x, const float* __restrict__ cw,
    const float* __restrict__ cb, float* __restrict__ actF, half_t* __restrict__ actB)
{
    const int t = blockIdx.x, b = blockIdx.y;
    const int idc = x[b * T_ + t];
    const int idp = (t > 0) ? x[b * T_ + t - 1] : -1;
    const size_t bt = (size_t)b * T_ + t;
    for (int c = threadIdx.x; c < 512; c += 256) {
        float v = cw[(c * 256 + idc) * 2 + 1] + cb[c];
        if (idp >= 0) v += cw[(c * 256 + idp) * 2 + 0];
        actF[bt * 512 + c] = v;
        actB[bt * 576 + c] = f2h(v);
    }
}

// aux channels of X: actB[t][512+j] = fp16(h[b][j][t]) for j<28 else 0
__global__ __launch_bounds__(256) void packh_kernel(
    const float* __restrict__ h, half_t* __restrict__ actB)
{
    const int idx = blockIdx.x * 256 + threadIdx.x;     // 8192*64
    const int j = idx & 63;
    const int bt = idx >> 6;
    const int b = bt >> 12, t = bt & 4095;
    const float v = (j < 28) ? h[((size_t)b * NAUX_ + j) * T_ + t] : 0.f;
    actB[(size_t)bt * 576 + 512 + j] = f2h(v);
}

// ---------------------------------------------------------------------------
// Weight packing v2: clean float4 reads; each thread emits both taps.
// Wall rows: [0,512)=sig cur, [512,1024)=sig past, [1024,1536)=tanh cur,
// [1536,2048)=tanh past. Columns [0,512) from dil weights.
// ---------------------------------------------------------------------------
__global__ __launch_bounds__(256) void packwall_kernel(
    const float* __restrict__ dsw, const float* __restrict__ dtw,
    half_t* __restrict__ Wall)
{
    const int idx = blockIdx.x * 256 + threadIdx.x;     // 30*512*64
    const int cg = idx & 63;
    const int rr = (idx >> 6) & 511;
    const int l = idx >> 15;
    const int c0 = cg * 8;
    const size_t base = (((size_t)l * 512 + rr) * 512 + c0) * 2;

    {
        const float4* p = (const float4*)(dsw + base);
        const float4 q0 = p[0], q1 = p[1], q2 = p[2], q3 = p[3];
        f16x8 cur = {f2h(q0.y), f2h(q0.w), f2h(q1.y), f2h(q1.w),
                     f2h(q2.y), f2h(q2.w), f2h(q3.y), f2h(q3.w)};
        f16x8 pst = {f2h(q0.x), f2h(q0.z), f2h(q1.x), f2h(q1.z),
                     f2h(q2.x), f2h(q2.z), f2h(q3.x), f2h(q3.z)};
        *(f16x8*)&Wall[((size_t)l * 2048 + rr) * 576 + c0] = cur;
        *(f16x8*)&Wall[((size_t)l * 2048 + 512 + rr) * 576 + c0] = pst;
    }
    {
        const float4* p = (const float4*)(dtw + base);
        const float4 q0 = p[0], q1 = p[1], q2 = p[2], q3 = p[3];
        f16x8 cur = {f2h(q0.y), f2h(q0.w), f2h(q1.y), f2h(q1.w),
                     f2h(q2.y), f2h(q2.w), f2h(q3.y), f2h(q3.w)};
        f16x8 pst = {f2h(q0.x), f2h(q0.z), f2h(q1.x), f2h(q1.z),
                     f2h(q2.x), f2h(q2.z), f2h(q3.x), f2h(q3.z)};
        *(f16x8*)&Wall[((size_t)l * 2048 + 1024 + rr) * 576 + c0] = cur;
        *(f16x8*)&Wall[((size_t)l * 2048 + 1536 + rr) * 576 + c0] = pst;
    }
}

// aux columns [512,576) of Wall: asw/atw into cur rows, zeros into past rows
__global__ __launch_bounds__(256) void packaux_kernel(
    const float* __restrict__ asw, const float* __restrict__ atw,
    half_t* __restrict__ Wall)
{
    const int idx = blockIdx.x * 256 + threadIdx.x;     // 30*512*8
    const int j8 = idx & 7;
    const int rr = (idx >> 3) & 511;
    const int l = idx >> 12;
    f16x8 vs = {}, vt = {}, z = {};
#pragma unroll
    for (int e = 0; e < 8; e++) {
        const int j = j8 * 8 + e;
        if (j < NAUX_) {
            vs[e] = f2h(asw[((size_t)l * 512 + rr) * NAUX_ + j]);
            vt[e] = f2h(atw[((size_t)l * 512 + rr) * NAUX_ + j]);
        }
    }
    const size_t c = 512 + j8 * 8;
    *(f16x8*)&Wall[((size_t)l * 2048 + rr) * 576 + c] = vs;
    *(f16x8*)&Wall[((size_t)l * 2048 + 512 + rr) * 576 + c] = z;
    *(f16x8*)&Wall[((size_t)l * 2048 + 1024 + rr) * 576 + c] = vt;
    *(f16x8*)&Wall[((size_t)l * 2048 + 1536 + rr) * 576 + c] = z;
}

__global__ __launch_bounds__(256) void packsr_kernel(
    const float* __restrict__ rsw, const float* __restrict__ skw,
    half_t* __restrict__ Wsr)
{
    const int idx = blockIdx.x * 256 + threadIdx.x;     // 30*768*128
    const int c = (idx & 127) * 4;
    const int r = (idx >> 7) % 768;
    const int l = idx / (128 * 768);
    const float4 v = (r < 512)
        ? *(const float4*)&rsw[((size_t)l * 512 + r) * 512 + c]
        : *(const float4*)&skw[((size_t)l * 256 + (r - 512)) * 512 + c];
    f16x4 o = {f2h(v.x), f2h(v.y), f2h(v.z), f2h(v.w)};
    *(f16x4*)(Wsr + ((size_t)l * 768 + r) * 512 + c) = o;
}

__global__ __launch_bounds__(256) void packpost_kernel(
    const float* __restrict__ p1w, const float* __restrict__ p2w,
    const float* __restrict__ lw, half_t* __restrict__ Wpost)
{
    const int idx = blockIdx.x * 256 + threadIdx.x;     // 3*256*64
    const int c = (idx & 63) * 4;
    const int r = (idx >> 6) & 255;
    const int mi = idx >> 14;
    const float* src = (mi == 0) ? p1w : (mi == 1) ? p2w : lw;
    const float4 v = *(const float4*)&src[(size_t)r * 256 + c];
    f16x4 o = {f2h(v.x), f2h(v.y), f2h(v.z), f2h(v.w)};
    *(f16x4*)(Wpost + (size_t)mi * 65536 + (size_t)r * 256 + c) = o;
}

__global__ __launch_bounds__(256) void packbias_kernel(
    const float* __restrict__ dsb, const float* __restrict__ asb,
    const float* __restrict__ dtb, const float* __restrict__ atb,
    const float* __restrict__ rsb, const float* __restrict__ skb,
    float* __restrict__ biasAll, float* __restrict__ biasSr)
{
    const int idx = blockIdx.x * 256 + threadIdx.x;
    if (idx < 30 * 2048) {
        const int l = idx >> 11, r = idx & 2047;
        float v = 0.f;
        if (r < 512) v = dsb[l * 512 + r] + asb[l * 512 + r];
        else if (r >= 1024 && r < 1536) v = dtb[l * 512 + (r - 1024)] + atb[l * 512 + (r - 1024)];
        biasAll[idx] = v;
    } else if (idx < 30 * 2048 + 30 * 768) {
        const int j = idx - 30 * 2048;
        const int l = j / 768, r = j % 768;
        biasSr[j] = (r < 512) ? rsb[l * 512 + r] : skb[l * 256 + (r - 512)];
    }
}

// ---------------------------------------------------------------------------
extern "C" void kernel_launch(void* const* d_in, const int* in_sizes, int n_in,
                              void* d_out, int out_size, void* d_ws, size_t ws_size,
                              hipStream_t stream)
{
    (void)in_sizes; (void)n_in; (void)out_size; (void)ws_size;

    const int* x = (const int*)d_in[0];
    const float* h = (const float*)d_in[1];
    const float* causal_w = (const float*)d_in[2];
    const float* causal_b = (const float*)d_in[3];
    const float* dsw = (const float*)d_in[4];
    const float* dsb = (const float*)d_in[5];
    const float* dtw = (const float*)d_in[6];
    const float* dtb = (const float*)d_in[7];
    const float* asw = (const float*)d_in[8];
    const float* asb = (const float*)d_in[9];
    const float* atw = (const float*)d_in[10];
    const float* atb = (const float*)d_in[11];
    const float* skw = (const float*)d_in[12];
    const float* skb = (const float*)d_in[13];
    const float* rsw = (const float*)d_in[14];
    const float* rsb = (const float*)d_in[15];
    const float* p1w = (const float*)d_in[16];
    const float* p1b = (const float*)d_in[17];
    const float* p2w = (const float*)d_in[18];
    const float* p2b = (const float*)d_in[19];
    const float* lw  = (const float*)d_in[20];
    const float* lb  = (const float*)d_in[21];

    char* ws = (char*)d_ws;
    size_t off = 0;
    auto alloc = [&](size_t bytes) { char* p = ws + off; off += (bytes + 255) & ~(size_t)255; return p; };

    half_t* Wall   = (half_t*)alloc((size_t)L_ * 2048 * 576 * 2);
    half_t* Wsr    = (half_t*)alloc((size_t)L_ * 768 * 512 * 2);
    half_t* Wpost  = (half_t*)alloc((size_t)3 * 256 * 256 * 2);
    float*  biasAll= (float*) alloc((size_t)L_ * 2048 * 4);
    float*  biasSr = (float*) alloc((size_t)L_ * 768 * 4);
    float*  actF   = (float*) alloc((size_t)B_ * T_ * 512 * 4);
    half_t* actB   = (half_t*)alloc((size_t)B_ * T_ * 576 * 2);
    half_t* Z      = (half_t*)alloc((size_t)B_ * T_ * 2048 * 2);
    half_t* g      = (half_t*)alloc((size_t)B_ * T_ * 512 * 2);
    float*  skipAcc= (float*) alloc((size_t)B_ * T_ * 256 * 4);
    half_t* pA     = (half_t*)alloc((size_t)B_ * T_ * 256 * 2);
    half_t* pB     = (half_t*)alloc((size_t)B_ * T_ * 256 * 2);

    hipMemsetAsync(skipAcc, 0, (size_t)B_ * T_ * 256 * 4, stream);

    packwall_kernel<<<30 * 512 * 64 / 256, 256, 0, stream>>>(dsw, dtw, Wall);
    packaux_kernel<<<30 * 512 * 8 / 256, 256, 0, stream>>>(asw, atw, Wall);
    packsr_kernel<<<30 * 768 * 128 / 256, 256, 0, stream>>>(rsw, skw, Wsr);
    packpost_kernel<<<3 * 256 * 64 / 256, 256, 0, stream>>>(p1w, p2w, lw, Wpost);
    packbias_kernel<<<(30 * 2048 + 30 * 768 + 255) / 256, 256, 0, stream>>>(
        dsb, asb, dtb, atb, rsb, skb, biasAll, biasSr);
    packh_kernel<<<B_ * T_ * 64 / 256, 256, 0, stream>>>(h, actB);
    embed_kernel<<<dim3(T_, B_), 256, 0, stream>>>(x, causal_w, causal_b, actF, actB);

    for (int l = 0; l < L_; l++) {
        const int dil = 1 << (l % 10);
        gemm_mfma<0><<<dim3(32, 16, B_), 256, 0, stream>>>(
            actB, Wall + (size_t)l * 2048 * 576, biasAll + (size_t)l * 2048, Z, 2048, 576,
            nullptr, nullptr, nullptr);
        gating_kernel<<<B_ * T_ * 128 / 256, 256, 0, stream>>>(Z, g, dil);
        gemm_mfma<3><<<dim3(32, 6, B_), 256, 0, stream>>>(
            g, Wsr + (size_t)l * 768 * 512, biasSr + (size_t)l * 768, nullptr, 768, 512,
            actF, actB, skipAcc);
    }

    relupack_kernel<<<B_ * T_ * 64 / 256, 256, 0, stream>>>(skipAcc, pA);
    gemm_mfma<1><<<dim3(32, 2, B_), 256, 0, stream>>>(pA, Wpost, p1b, pB, 256, 256,
                                                      nullptr, nullptr, nullptr);
    gemm_mfma<0><<<dim3(32, 2, B_), 256, 0, stream>>>(pB, Wpost + 65536, p2b, pA, 256, 256,
                                                      nullptr, nullptr, nullptr);
    gemm_mfma<2><<<dim3(32, 2, B_), 256, 0, stream>>>(pA, Wpost + 131072, lb, d_out, 256, 256,
                                                      nullptr, nullptr, nullptr);
}

// Round 5
// 1747.914 us; speedup vs baseline: 10.2655x; 1.3547x over previous
//
#include <hip/hip_runtime.h>
#include <cstddef>

#define B_ 2
#define T_ 4096
#define NQ_ 256
#define NAUX_ 28
#define NR_ 512
#define NS_ 256
#define L_ 30

typedef _Float16 half_t;
typedef __attribute__((ext_vector_type(8))) _Float16 f16x8;
typedef __attribute__((ext_vector_type(4))) _Float16 f16x4;
typedef __attribute__((ext_vector_type(4))) float f32x4;

__device__ inline half_t f2h(float f) { return (half_t)f; }
__device__ inline float h2f(half_t h) { return (float)h; }

// async global->LDS, 16 B per lane; LDS dest = wave base + lane*16
__device__ __forceinline__ void gload16(const void* g, void* l) {
    __builtin_amdgcn_global_load_lds(
        (const __attribute__((address_space(1))) unsigned int*)g,
        (__attribute__((address_space(3))) unsigned int*)l, 16, 0, 0);
}

// ---------------------------------------------------------------------------
// Fused gates GEMM + gating.
// Wg: [1024][1088] fp16. Row r: group gidx=r>>6, rsub=r&63; rsub<32 -> sig
// channel gidx*32+rsub, else tanh channel gidx*32+rsub-32.
// Cols: [0,512)=W_cur, [512,1024)=W_past, [1024,1088)=aux (64, zero-padded).
// X_ext(t) = [actB[t][0..512) ; actB[t-dil][0..512) (0 if t<dil) ; actB[t][512..576)]
// Epilogue: g[t][c] = sigmoid(s)*tanh(t) in-register (fragments i / i+2).
// grid (32, 8, B), 256 threads.
// ---------------------------------------------------------------------------
__global__ __launch_bounds__(256) void gates_gemm(
    const half_t* __restrict__ actB, const half_t* __restrict__ Wg,
    const float* __restrict__ biasG, half_t* __restrict__ g,
    const half_t* __restrict__ zbuf, int dil)
{
    __shared__ __align__(16) half_t sA[128 * 64];  // W tile
    __shared__ __align__(16) half_t sB[128 * 64];  // X tile

    const int tid = threadIdx.x;
    const int b = blockIdx.z;
    const int tB = blockIdx.x * 128;
    const int mB = blockIdx.y * 128;
    const int w = tid >> 6, lane = tid & 63;
    const int wm = w >> 1, wn = w & 1;
    const int l15 = lane & 15, lg = lane >> 4;
    const int rr = lane >> 3, cc = lane & 7;
    const int sc8 = cc ^ rr;               // swizzled chunk for staging

    f32x4 acc[4][4] = {};

    const half_t* Wb = Wg + (size_t)mB * 1088;

    for (int kc = 0; kc < 17; kc++) {
#pragma unroll
        for (int it = 0; it < 4; it++) {
            const int row = w * 32 + it * 8 + rr;
            gload16(Wb + (size_t)row * 1088 + kc * 64 + sc8 * 8,
                    &sA[(w * 32 + it * 8) * 64]);
        }
#pragma unroll
        for (int it = 0; it < 4; it++) {
            const int t = tB + w * 32 + it * 8 + rr;
            const half_t* p;
            if (kc < 8) {
                p = actB + ((size_t)b * T_ + t) * 576 + kc * 64;
            } else if (kc < 16) {
                const int tp = t - dil;
                p = (tp >= 0) ? actB + ((size_t)b * T_ + tp) * 576 + (kc - 8) * 64
                              : zbuf;
            } else {
                p = actB + ((size_t)b * T_ + t) * 576 + 512;
            }
            gload16(p + sc8 * 8, &sB[(w * 32 + it * 8) * 64]);
        }
        __syncthreads();
#pragma unroll
        for (int s = 0; s < 2; s++) {
            f16x8 av[4], bv[4];
#pragma unroll
            for (int i = 0; i < 4; i++) {
                const int r = wm * 64 + i * 16 + l15;
                av[i] = *(const f16x8*)&sA[r * 64 + (((s * 4 + lg) ^ (l15 & 7)) * 8)];
            }
#pragma unroll
            for (int j = 0; j < 4; j++) {
                const int r = wn * 64 + j * 16 + l15;
                bv[j] = *(const f16x8*)&sB[r * 64 + (((s * 4 + lg) ^ (l15 & 7)) * 8)];
            }
#pragma unroll
            for (int i = 0; i < 4; i++)
#pragma unroll
                for (int j = 0; j < 4; j++)
                    acc[i][j] = __builtin_amdgcn_mfma_f32_16x16x32_f16(av[i], bv[j], acc[i][j], 0, 0, 0);
        }
        __syncthreads();
    }

    const int gidx = blockIdx.y * 2 + wm;
    const int t0 = tB + wn * 64 + l15;
#pragma unroll
    for (int i = 0; i < 2; i++) {
        const int c = gidx * 32 + i * 16 + lg * 4;
        const float4 bs = *(const float4*)&biasG[gidx * 64 + i * 16 + lg * 4];
        const float4 bt4 = *(const float4*)&biasG[gidx * 64 + 32 + i * 16 + lg * 4];
        const float bsa[4] = {bs.x, bs.y, bs.z, bs.w};
        const float bta[4] = {bt4.x, bt4.y, bt4.z, bt4.w};
#pragma unroll
        for (int j = 0; j < 4; j++) {
            const int t = t0 + j * 16;
            f16x4 o;
#pragma unroll
            for (int e = 0; e < 4; e++) {
                const float sv = acc[i][j][e] + bsa[e];
                const float tv = acc[i + 2][j][e] + bta[e];
                const float sg = 1.f / (1.f + __expf(-sv));
                const float ex = __expf(-2.f * tv);
                const float th = (1.f - ex) / (1.f + ex);
                o[e] = f2h(sg * th);
            }
            *(f16x4*)(g + ((size_t)b * T_ + t) * 512 + c) = o;
        }
    }
}

// ---------------------------------------------------------------------------
// Generic fp16 MFMA GEMM (same structure), for sr + post layers.
// EPI: 0 = fp16 store, 1 = fp16+relu, 2 = f32 store,
//      3 = fused res/skip (m<512: actF+=, mirror to actB; m>=512: skipAcc+=)
// ---------------------------------------------------------------------------
template<int EPI>
__global__ __launch_bounds__(256) void gemm_mfma(
    const half_t* __restrict__ X, const half_t* __restrict__ W,
    const float* __restrict__ bias, void* __restrict__ out, int M, int K,
    float* __restrict__ actF, half_t* __restrict__ actB,
    float* __restrict__ skipAcc)
{
    __shared__ __align__(16) half_t sA[128 * 64];
    __shared__ __align__(16) half_t sB[128 * 64];

    const int tid = threadIdx.x;
    const int b = blockIdx.z;
    const int tB = blockIdx.x * 128;
    const int mB = blockIdx.y * 128;
    const int w = tid >> 6, lane = tid & 63;
    const int wm = w >> 1, wn = w & 1;
    const int l15 = lane & 15, lg = lane >> 4;
    const int rr = lane >> 3, cc = lane & 7;
    const int sc8 = cc ^ rr;

    f32x4 acc[4][4] = {};

    const half_t* Xb = X + ((size_t)b * T_ + tB) * K;
    const half_t* Wb = W + (size_t)mB * K;

    const int nk = K >> 6;
    for (int kc = 0; kc < nk; kc++) {
        const int k0 = kc << 6;
#pragma unroll
        for (int it = 0; it < 4; it++) {
            const int row = w * 32 + it * 8 + rr;
            gload16(Wb + (size_t)row * K + k0 + sc8 * 8, &sA[(w * 32 + it * 8) * 64]);
            gload16(Xb + (size_t)row * K + k0 + sc8 * 8, &sB[(w * 32 + it * 8) * 64]);
        }
        __syncthreads();
#pragma unroll
        for (int s = 0; s < 2; s++) {
            f16x8 av[4], bv[4];
#pragma unroll
            for (int i = 0; i < 4; i++) {
                const int r = wm * 64 + i * 16 + l15;
                av[i] = *(const f16x8*)&sA[r * 64 + (((s * 4 + lg) ^ (l15 & 7)) * 8)];
            }
#pragma unroll
            for (int j = 0; j < 4; j++) {
                const int r = wn * 64 + j * 16 + l15;
                bv[j] = *(const f16x8*)&sB[r * 64 + (((s * 4 + lg) ^ (l15 & 7)) * 8)];
            }
#pragma unroll
            for (int i = 0; i < 4; i++)
#pragma unroll
                for (int j = 0; j < 4; j++)
                    acc[i][j] = __builtin_amdgcn_mfma_f32_16x16x32_f16(av[i], bv[j], acc[i][j], 0, 0, 0);
        }
        __syncthreads();
    }

    const int n0 = tB + wn * 64 + l15;
#pragma unroll
    for (int i = 0; i < 4; i++) {
        const int m = mB + wm * 64 + i * 16 + lg * 4;
        float4 bv = make_float4(0.f, 0.f, 0.f, 0.f);
        if (bias) bv = *(const float4*)&bias[m];
#pragma unroll
        for (int j = 0; j < 4; j++) {
            const int t = n0 + j * 16;
            float o0 = acc[i][j][0] + bv.x, o1 = acc[i][j][1] + bv.y;
            float o2 = acc[i][j][2] + bv.z, o3 = acc[i][j][3] + bv.w;
            if (EPI == 1) {
                o0 = fmaxf(o0, 0.f); o1 = fmaxf(o1, 0.f);
                o2 = fmaxf(o2, 0.f); o3 = fmaxf(o3, 0.f);
            }
            if (EPI == 3) {
                const size_t bt = (size_t)b * T_ + t;
                if (mB < 512) {
                    const size_t o = bt * 512 + m;
                    float4 old = *(float4*)(actF + o);
                    const float4 nv = make_float4(old.x + o0, old.y + o1,
                                                  old.z + o2, old.w + o3);
                    *(float4*)(actF + o) = nv;
                    f16x4 mr = {f2h(nv.x), f2h(nv.y), f2h(nv.z), f2h(nv.w)};
                    *(f16x4*)(actB + bt * 576 + m) = mr;
                } else {
                    const size_t o = bt * 256 + (m - 512);
                    float4 s4 = *(float4*)(skipAcc + o);
                    s4.x += o0; s4.y += o1; s4.z += o2; s4.w += o3;
                    *(float4*)(skipAcc + o) = s4;
                }
            } else {
                const size_t off = ((size_t)b * T_ + t) * M + m;
                if (EPI == 2) {
                    *(float4*)((float*)out + off) = make_float4(o0, o1, o2, o3);
                } else {
                    f16x4 ov = {f2h(o0), f2h(o1), f2h(o2), f2h(o3)};
                    *(f16x4*)((half_t*)out + off) = ov;
                }
            }
        }
    }
}

// relu(skipAcc) -> fp16
__global__ __launch_bounds__(256) void relupack_kernel(
    const float* __restrict__ skipAcc, half_t* __restrict__ outp)
{
    const int idx = blockIdx.x * 256 + threadIdx.x;     // 8192*64
    const int c = (idx & 63) * 4;
    const int bt = idx >> 6;
    const float4 v = *(const float4*)(skipAcc + (size_t)bt * 256 + c);
    f16x4 o = {f2h(fmaxf(v.x, 0.f)), f2h(fmaxf(v.y, 0.f)),
               f2h(fmaxf(v.z, 0.f)), f2h(fmaxf(v.w, 0.f))};
    *(f16x4*)(outp + (size_t)bt * 256 + c) = o;
}

// ---------------------------------------------------------------------------
// Embed: actF[t][c] = cw[c][x[t]][1] + cw[c][x[t-1]][0] + cb[c]; fp16 mirror
// ---------------------------------------------------------------------------
__global__ __launch_bounds__(256) void embed_kernel(
    const int* __restrict__ x, const float* __restrict__ cw,
    const float* __restrict__ cb, float* __restrict__ actF, half_t* __restrict__ actB)
{
    const int t = blockIdx.x, b = blockIdx.y;
    const int idc = x[b * T_ + t];
    const int idp = (t > 0) ? x[b * T_ + t - 1] : -1;
    const size_t bt = (size_t)b * T_ + t;
    for (int c = threadIdx.x; c < 512; c += 256) {
        float v = cw[(c * 256 + idc) * 2 + 1] + cb[c];
        if (idp >= 0) v += cw[(c * 256 + idp) * 2 + 0];
        actF[bt * 512 + c] = v;
        actB[bt * 576 + c] = f2h(v);
    }
}

// aux channels: actB[t][512+j] = fp16(h[b][j][t]) for j<28 else 0
__global__ __launch_bounds__(256) void packh_kernel(
    const float* __restrict__ h, half_t* __restrict__ actB)
{
    const int idx = blockIdx.x * 256 + threadIdx.x;     // 8192*64
    const int j = idx & 63;
    const int bt = idx >> 6;
    const int b = bt >> 12, t = bt & 4095;
    const float v = (j < 28) ? h[((size_t)b * NAUX_ + j) * T_ + t] : 0.f;
    actB[(size_t)bt * 576 + 512 + j] = f2h(v);
}

// ---------------------------------------------------------------------------
// Pack gate weights: Wg[l][1024][1088].
// Thread: (l, r, kgrp) ; reads 16 floats (8 k, both taps) from dsw/dtw,
// writes cur chunk at col kgrp*8 and past chunk at col 512+kgrp*8.
// ---------------------------------------------------------------------------
__global__ __launch_bounds__(256) void packgate_kernel(
    const float* __restrict__ dsw, const float* __restrict__ dtw,
    half_t* __restrict__ Wg)
{
    const int idx = blockIdx.x * 256 + threadIdx.x;     // 30*1024*64
    const int kg = idx & 63;
    const int r = (idx >> 6) & 1023;
    const int l = idx >> 16;
    const int rsub = r & 63;
    const int c = (r >> 6) * 32 + (rsub & 31);
    const float* src = (rsub < 32) ? dsw : dtw;
    const int k0 = kg * 8;
    const float4* p = (const float4*)(src + (((size_t)l * 512 + c) * 512 + k0) * 2);
    const float4 q0 = p[0], q1 = p[1], q2 = p[2], q3 = p[3];
    f16x8 cur = {f2h(q0.y), f2h(q0.w), f2h(q1.y), f2h(q1.w),
                 f2h(q2.y), f2h(q2.w), f2h(q3.y), f2h(q3.w)};
    f16x8 pst = {f2h(q0.x), f2h(q0.z), f2h(q1.x), f2h(q1.z),
                 f2h(q2.x), f2h(q2.z), f2h(q3.x), f2h(q3.z)};
    half_t* row = Wg + ((size_t)l * 1024 + r) * 1088;
    *(f16x8*)&row[k0] = cur;
    *(f16x8*)&row[512 + k0] = pst;
}

// aux cols [1024,1088) of Wg
__global__ __launch_bounds__(256) void packgaux_kernel(
    const float* __restrict__ asw, const float* __restrict__ atw,
    half_t* __restrict__ Wg)
{
    const int idx = blockIdx.x * 256 + threadIdx.x;     // 30*1024*8
    const int j8 = idx & 7;
    const int r = (idx >> 3) & 1023;
    const int l = idx >> 13;
    const int rsub = r & 63;
    const int c = (r >> 6) * 32 + (rsub & 31);
    const float* src = (rsub < 32) ? asw : atw;
    f16x8 v = {};
#pragma unroll
    for (int e = 0; e < 8; e++) {
        const int j = j8 * 8 + e;
        if (j < NAUX_) v[e] = f2h(src[((size_t)l * 512 + c) * NAUX_ + j]);
    }
    *(f16x8*)&Wg[((size_t)l * 1024 + r) * 1088 + 1024 + j8 * 8] = v;
}

__global__ __launch_bounds__(256) void packsr_kernel(
    const float* __restrict__ rsw, const float* __restrict__ skw,
    half_t* __restrict__ Wsr)
{
    const int idx = blockIdx.x * 256 + threadIdx.x;     // 30*768*128
    const int c = (idx & 127) * 4;
    const int r = (idx >> 7) % 768;
    const int l = idx / (128 * 768);
    const float4 v = (r < 512)
        ? *(const float4*)&rsw[((size_t)l * 512 + r) * 512 + c]
        : *(const float4*)&skw[((size_t)l * 256 + (r - 512)) * 512 + c];
    f16x4 o = {f2h(v.x), f2h(v.y), f2h(v.z), f2h(v.w)};
    *(f16x4*)(Wsr + ((size_t)l * 768 + r) * 512 + c) = o;
}

__global__ __launch_bounds__(256) void packpost_kernel(
    const float* __restrict__ p1w, const float* __restrict__ p2w,
    const float* __restrict__ lw, half_t* __restrict__ Wpost)
{
    const int idx = blockIdx.x * 256 + threadIdx.x;     // 3*256*64
    const int c = (idx & 63) * 4;
    const int r = (idx >> 6) & 255;
    const int mi = idx >> 14;
    const float* src = (mi == 0) ? p1w : (mi == 1) ? p2w : lw;
    const float4 v = *(const float4*)&src[(size_t)r * 256 + c];
    f16x4 o = {f2h(v.x), f2h(v.y), f2h(v.z), f2h(v.w)};
    *(f16x4*)(Wpost + (size_t)mi * 65536 + (size_t)r * 256 + c) = o;
}

// biasG rows follow Wg row mapping; biasSr unchanged
__global__ __launch_bounds__(256) void packbias_kernel(
    const float* __restrict__ dsb, const float* __restrict__ asb,
    const float* __restrict__ dtb, const float* __restrict__ atb,
    const float* __restrict__ rsb, const float* __restrict__ skb,
    float* __restrict__ biasG, float* __restrict__ biasSr)
{
    const int idx = blockIdx.x * 256 + threadIdx.x;
    if (idx < 30 * 1024) {
        const int l = idx >> 10, r = idx & 1023;
        const int rsub = r & 63;
        const int c = (r >> 6) * 32 + (rsub & 31);
        const float v = (rsub < 32) ? (dsb[l * 512 + c] + asb[l * 512 + c])
                                    : (dtb[l * 512 + c] + atb[l * 512 + c]);
        biasG[idx] = v;
    } else if (idx < 30 * 1024 + 30 * 768) {
        const int j = idx - 30 * 1024;
        const int l = j / 768, r = j % 768;
        biasSr[j] = (r < 512) ? rsb[l * 512 + r] : skb[l * 256 + (r - 512)];
    }
}

// ---------------------------------------------------------------------------
extern "C" void kernel_launch(void* const* d_in, const int* in_sizes, int n_in,
                              void* d_out, int out_size, void* d_ws, size_t ws_size,
                              hipStream_t stream)
{
    (void)in_sizes; (void)n_in; (void)out_size; (void)ws_size;

    const int* x = (const int*)d_in[0];
    const float* h = (const float*)d_in[1];
    const float* causal_w = (const float*)d_in[2];
    const float* causal_b = (const float*)d_in[3];
    const float* dsw = (const float*)d_in[4];
    const float* dsb = (const float*)d_in[5];
    const float* dtw = (const float*)d_in[6];
    const float* dtb = (const float*)d_in[7];
    const float* asw = (const float*)d_in[8];
    const float* asb = (const float*)d_in[9];
    const float* atw = (const float*)d_in[10];
    const float* atb = (const float*)d_in[11];
    const float* skw = (const float*)d_in[12];
    const float* skb = (const float*)d_in[13];
    const float* rsw = (const float*)d_in[14];
    const float* rsb = (const float*)d_in[15];
    const float* p1w = (const float*)d_in[16];
    const float* p1b = (const float*)d_in[17];
    const float* p2w = (const float*)d_in[18];
    const float* p2b = (const float*)d_in[19];
    const float* lw  = (const float*)d_in[20];
    const float* lb  = (const float*)d_in[21];

    char* ws = (char*)d_ws;
    size_t off = 0;
    auto alloc = [&](size_t bytes) { char* p = ws + off; off += (bytes + 255) & ~(size_t)255; return p; };

    half_t* Wg     = (half_t*)alloc((size_t)L_ * 1024 * 1088 * 2);
    half_t* Wsr    = (half_t*)alloc((size_t)L_ * 768 * 512 * 2);
    half_t* Wpost  = (half_t*)alloc((size_t)3 * 256 * 256 * 2);
    float*  biasG  = (float*) alloc((size_t)L_ * 1024 * 4);
    float*  biasSr = (float*) alloc((size_t)L_ * 768 * 4);
    float*  actF   = (float*) alloc((size_t)B_ * T_ * 512 * 4);
    half_t* actB   = (half_t*)alloc((size_t)B_ * T_ * 576 * 2);
    half_t* g      = (half_t*)alloc((size_t)B_ * T_ * 512 * 2);
    float*  skipAcc= (float*) alloc((size_t)B_ * T_ * 256 * 4);
    half_t* zbuf   = (half_t*)alloc(256);
    half_t* pA     = (half_t*)alloc((size_t)B_ * T_ * 256 * 2);
    half_t* pB     = (half_t*)alloc((size_t)B_ * T_ * 256 * 2);

    hipMemsetAsync(skipAcc, 0, (size_t)B_ * T_ * 256 * 4 + 256, stream);  // skipAcc + zbuf

    packgate_kernel<<<30 * 1024 * 64 / 256, 256, 0, stream>>>(dsw, dtw, Wg);
    packgaux_kernel<<<30 * 1024 * 8 / 256, 256, 0, stream>>>(asw, atw, Wg);
    packsr_kernel<<<30 * 768 * 128 / 256, 256, 0, stream>>>(rsw, skw, Wsr);
    packpost_kernel<<<3 * 256 * 64 / 256, 256, 0, stream>>>(p1w, p2w, lw, Wpost);
    packbias_kernel<<<(30 * 1024 + 30 * 768 + 255) / 256, 256, 0, stream>>>(
        dsb, asb, dtb, atb, rsb, skb, biasG, biasSr);
    packh_kernel<<<B_ * T_ * 64 / 256, 256, 0, stream>>>(h, actB);
    embed_kernel<<<dim3(T_, B_), 256, 0, stream>>>(x, causal_w, causal_b, actF, actB);

    for (int l = 0; l < L_; l++) {
        const int dil = 1 << (l % 10);
        gates_gemm<<<dim3(32, 8, B_), 256, 0, stream>>>(
            actB, Wg + (size_t)l * 1024 * 1088, biasG + (size_t)l * 1024, g, zbuf, dil);
        gemm_mfma<3><<<dim3(32, 6, B_), 256, 0, stream>>>(
            g, Wsr + (size_t)l * 768 * 512, biasSr + (size_t)l * 768, nullptr, 768, 512,
            actF, actB, skipAcc);
    }

    relupack_kernel<<<B_ * T_ * 64 / 256, 256, 0, stream>>>(skipAcc, pA);
    gemm_mfma<1><<<dim3(32, 2, B_), 256, 0, stream>>>(pA, Wpost, p1b, pB, 256, 256,
                                                      nullptr, nullptr, nullptr);
    gemm_mfma<0><<<dim3(32, 2, B_), 256, 0, stream>>>(pB, Wpost + 65536, p2b, pA, 256, 256,
                                                      nullptr, nullptr, nullptr);
    gemm_mfma<2><<<dim3(32, 2, B_), 256, 0, stream>>>(pA, Wpost + 131072, lb, d_out, 256, 256,
                                                      nullptr, nullptr, nullptr);
}

// Round 6
// 1550.399 us; speedup vs baseline: 11.5733x; 1.1274x over previous
//
#include <hip/hip_runtime.h>
#include <cstddef>

#define B_ 2
#define T_ 4096
#define NQ_ 256
#define NAUX_ 28
#define NR_ 512
#define NS_ 256
#define L_ 30

typedef _Float16 half_t;
typedef __attribute__((ext_vector_type(8))) _Float16 f16x8;
typedef __attribute__((ext_vector_type(4))) _Float16 f16x4;
typedef __attribute__((ext_vector_type(4))) float f32x4;

__device__ inline half_t f2h(float f) { return (half_t)f; }
__device__ inline float h2f(half_t h) { return (float)h; }

// async global->LDS, 16 B per lane; LDS dest = wave base + lane*16
__device__ __forceinline__ void gload16(const void* g, void* l) {
    __builtin_amdgcn_global_load_lds(
        (const __attribute__((address_space(1))) unsigned int*)g,
        (__attribute__((address_space(3))) unsigned int*)l, 16, 0, 0);
}

// ---------------------------------------------------------------------------
// Fused gates GEMM + gating.
// Wg: [1024][1088] fp16. Row r: group gidx=r>>6, rsub=r&63; rsub<32 -> sig
// channel gidx*32+rsub, else tanh channel gidx*32+rsub-32.
// Cols: [0,512)=W_cur, [512,1024)=W_past, [1024,1088)=aux (64, zero-padded).
// X_ext(t) = [actB[t][0..512) ; actB[t-dil][0..512) (0 if t<dil) ; actB[t][512..576)]
// Epilogue: g[t][c] = sigmoid(s)*tanh(t) in-register (fragments i / i+2).
// grid (32, 8, B), 256 threads.
// ---------------------------------------------------------------------------
__global__ __launch_bounds__(256) void gates_gemm(
    const half_t* __restrict__ actB, const half_t* __restrict__ Wg,
    const float* __restrict__ biasG, half_t* __restrict__ g,
    const half_t* __restrict__ zbuf, int dil)
{
    __shared__ __align__(16) half_t sA[128 * 64];  // W tile
    __shared__ __align__(16) half_t sB[128 * 64];  // X tile

    const int tid = threadIdx.x;
    const int b = blockIdx.z;
    const int tB = blockIdx.x * 128;
    const int mB = blockIdx.y * 128;
    const int w = tid >> 6, lane = tid & 63;
    const int wm = w >> 1, wn = w & 1;
    const int l15 = lane & 15, lg = lane >> 4;
    const int rr = lane >> 3, cc = lane & 7;
    const int sc8 = cc ^ rr;               // swizzled chunk for staging

    f32x4 acc[4][4] = {};

    const half_t* Wb = Wg + (size_t)mB * 1088;

    for (int kc = 0; kc < 17; kc++) {
#pragma unroll
        for (int it = 0; it < 4; it++) {
            const int row = w * 32 + it * 8 + rr;
            gload16(Wb + (size_t)row * 1088 + kc * 64 + sc8 * 8,
                    &sA[(w * 32 + it * 8) * 64]);
        }
#pragma unroll
        for (int it = 0; it < 4; it++) {
            const int t = tB + w * 32 + it * 8 + rr;
            const half_t* p;
            if (kc < 8) {
                p = actB + ((size_t)b * T_ + t) * 576 + kc * 64;
            } else if (kc < 16) {
                const int tp = t - dil;
                p = (tp >= 0) ? actB + ((size_t)b * T_ + tp) * 576 + (kc - 8) * 64
                              : zbuf;
            } else {
                p = actB + ((size_t)b * T_ + t) * 576 + 512;
            }
            gload16(p + sc8 * 8, &sB[(w * 32 + it * 8) * 64]);
        }
        __syncthreads();
#pragma unroll
        for (int s = 0; s < 2; s++) {
            f16x8 av[4], bv[4];
#pragma unroll
            for (int i = 0; i < 4; i++) {
                const int r = wm * 64 + i * 16 + l15;
                av[i] = *(const f16x8*)&sA[r * 64 + (((s * 4 + lg) ^ (l15 & 7)) * 8)];
            }
#pragma unroll
            for (int j = 0; j < 4; j++) {
                const int r = wn * 64 + j * 16 + l15;
                bv[j] = *(const f16x8*)&sB[r * 64 + (((s * 4 + lg) ^ (l15 & 7)) * 8)];
            }
#pragma unroll
            for (int i = 0; i < 4; i++)
#pragma unroll
                for (int j = 0; j < 4; j++)
                    acc[i][j] = __builtin_amdgcn_mfma_f32_16x16x32_f16(av[i], bv[j], acc[i][j], 0, 0, 0);
        }
        __syncthreads();
    }

    const int gidx = blockIdx.y * 2 + wm;
    const int t0 = tB + wn * 64 + l15;
#pragma unroll
    for (int i = 0; i < 2; i++) {
        const int c = gidx * 32 + i * 16 + lg * 4;
        const float4 bs = *(const float4*)&biasG[gidx * 64 + i * 16 + lg * 4];
        const float4 bt4 = *(const float4*)&biasG[gidx * 64 + 32 + i * 16 + lg * 4];
        const float bsa[4] = {bs.x, bs.y, bs.z, bs.w};
        const float bta[4] = {bt4.x, bt4.y, bt4.z, bt4.w};
#pragma unroll
        for (int j = 0; j < 4; j++) {
            const int t = t0 + j * 16;
            f16x4 o;
#pragma unroll
            for (int e = 0; e < 4; e++) {
                const float sv = acc[i][j][e] + bsa[e];
                const float tv = acc[i + 2][j][e] + bta[e];
                const float sg = 1.f / (1.f + __expf(-sv));
                const float ex = __expf(-2.f * tv);
                const float th = (1.f - ex) / (1.f + ex);
                o[e] = f2h(sg * th);
            }
            *(f16x4*)(g + ((size_t)b * T_ + t) * 512 + c) = o;
        }
    }
}

// ---------------------------------------------------------------------------
// Generic fp16 MFMA GEMM (same structure), for sr + post layers.
// EPI: 0 = fp16 store, 1 = fp16+relu, 2 = f32 store,
//      3 = fused res/skip, all-fp16 state:
//          m<512 : actB[t][m] += delta (fp16 read-add-write)
//          m>=512: skipH[t][m-512] += delta (fp16 read-add-write)
// ---------------------------------------------------------------------------
template<int EPI>
__global__ __launch_bounds__(256) void gemm_mfma(
    const half_t* __restrict__ X, const half_t* __restrict__ W,
    const float* __restrict__ bias, void* __restrict__ out, int M, int K,
    half_t* __restrict__ actB, half_t* __restrict__ skipH)
{
    __shared__ __align__(16) half_t sA[128 * 64];
    __shared__ __align__(16) half_t sB[128 * 64];

    const int tid = threadIdx.x;
    const int b = blockIdx.z;
    const int tB = blockIdx.x * 128;
    const int mB = blockIdx.y * 128;
    const int w = tid >> 6, lane = tid & 63;
    const int wm = w >> 1, wn = w & 1;
    const int l15 = lane & 15, lg = lane >> 4;
    const int rr = lane >> 3, cc = lane & 7;
    const int sc8 = cc ^ rr;

    f32x4 acc[4][4] = {};

    const half_t* Xb = X + ((size_t)b * T_ + tB) * K;
    const half_t* Wb = W + (size_t)mB * K;

    const int nk = K >> 6;
    for (int kc = 0; kc < nk; kc++) {
        const int k0 = kc << 6;
#pragma unroll
        for (int it = 0; it < 4; it++) {
            const int row = w * 32 + it * 8 + rr;
            gload16(Wb + (size_t)row * K + k0 + sc8 * 8, &sA[(w * 32 + it * 8) * 64]);
            gload16(Xb + (size_t)row * K + k0 + sc8 * 8, &sB[(w * 32 + it * 8) * 64]);
        }
        __syncthreads();
#pragma unroll
        for (int s = 0; s < 2; s++) {
            f16x8 av[4], bv[4];
#pragma unroll
            for (int i = 0; i < 4; i++) {
                const int r = wm * 64 + i * 16 + l15;
                av[i] = *(const f16x8*)&sA[r * 64 + (((s * 4 + lg) ^ (l15 & 7)) * 8)];
            }
#pragma unroll
            for (int j = 0; j < 4; j++) {
                const int r = wn * 64 + j * 16 + l15;
                bv[j] = *(const f16x8*)&sB[r * 64 + (((s * 4 + lg) ^ (l15 & 7)) * 8)];
            }
#pragma unroll
            for (int i = 0; i < 4; i++)
#pragma unroll
                for (int j = 0; j < 4; j++)
                    acc[i][j] = __builtin_amdgcn_mfma_f32_16x16x32_f16(av[i], bv[j], acc[i][j], 0, 0, 0);
        }
        __syncthreads();
    }

    const int n0 = tB + wn * 64 + l15;
#pragma unroll
    for (int i = 0; i < 4; i++) {
        const int m = mB + wm * 64 + i * 16 + lg * 4;
        float4 bv = make_float4(0.f, 0.f, 0.f, 0.f);
        if (bias) bv = *(const float4*)&bias[m];
#pragma unroll
        for (int j = 0; j < 4; j++) {
            const int t = n0 + j * 16;
            float o0 = acc[i][j][0] + bv.x, o1 = acc[i][j][1] + bv.y;
            float o2 = acc[i][j][2] + bv.z, o3 = acc[i][j][3] + bv.w;
            if (EPI == 1) {
                o0 = fmaxf(o0, 0.f); o1 = fmaxf(o1, 0.f);
                o2 = fmaxf(o2, 0.f); o3 = fmaxf(o3, 0.f);
            }
            if (EPI == 3) {
                const size_t bt = (size_t)b * T_ + t;
                half_t* p = (mB < 512) ? (actB + bt * 576 + m)
                                       : (skipH + bt * 256 + (m - 512));
                f16x4 old = *(const f16x4*)p;
                f16x4 nv = {f2h(h2f(old.x) + o0), f2h(h2f(old.y) + o1),
                            f2h(h2f(old.z) + o2), f2h(h2f(old.w) + o3)};
                *(f16x4*)p = nv;
            } else {
                const size_t off = ((size_t)b * T_ + t) * M + m;
                if (EPI == 2) {
                    *(float4*)((float*)out + off) = make_float4(o0, o1, o2, o3);
                } else {
                    f16x4 ov = {f2h(o0), f2h(o1), f2h(o2), f2h(o3)};
                    *(f16x4*)((half_t*)out + off) = ov;
                }
            }
        }
    }
}

// relu(skipH) -> fp16 dense
__global__ __launch_bounds__(256) void relupack_kernel(
    const half_t* __restrict__ skipH, half_t* __restrict__ outp)
{
    const int idx = blockIdx.x * 256 + threadIdx.x;     // 8192*64
    const int c = (idx & 63) * 4;
    const int bt = idx >> 6;
    const f16x4 v = *(const f16x4*)(skipH + (size_t)bt * 256 + c);
    f16x4 o = {f2h(fmaxf(h2f(v.x), 0.f)), f2h(fmaxf(h2f(v.y), 0.f)),
               f2h(fmaxf(h2f(v.z), 0.f)), f2h(fmaxf(h2f(v.w), 0.f))};
    *(f16x4*)(outp + (size_t)bt * 256 + c) = o;
}

// ---------------------------------------------------------------------------
// Embed: actB[t][c] = fp16(cw[c][x[t]][1] + cw[c][x[t-1]][0] + cb[c])
// ---------------------------------------------------------------------------
__global__ __launch_bounds__(256) void embed_kernel(
    const int* __restrict__ x, const float* __restrict__ cw,
    const float* __restrict__ cb, half_t* __restrict__ actB)
{
    const int t = blockIdx.x, b = blockIdx.y;
    const int idc = x[b * T_ + t];
    const int idp = (t > 0) ? x[b * T_ + t - 1] : -1;
    const size_t bt = (size_t)b * T_ + t;
    for (int c = threadIdx.x; c < 512; c += 256) {
        float v = cw[(c * 256 + idc) * 2 + 1] + cb[c];
        if (idp >= 0) v += cw[(c * 256 + idp) * 2 + 0];
        actB[bt * 576 + c] = f2h(v);
    }
}

// aux channels: actB[t][512+j] = fp16(h[b][j][t]) for j<28 else 0
__global__ __launch_bounds__(256) void packh_kernel(
    const float* __restrict__ h, half_t* __restrict__ actB)
{
    const int idx = blockIdx.x * 256 + threadIdx.x;     // 8192*64
    const int j = idx & 63;
    const int bt = idx >> 6;
    const int b = bt >> 12, t = bt & 4095;
    const float v = (j < 28) ? h[((size_t)b * NAUX_ + j) * T_ + t] : 0.f;
    actB[(size_t)bt * 576 + 512 + j] = f2h(v);
}

// ---------------------------------------------------------------------------
// Pack gate weights: Wg[l][1024][1088].
// ---------------------------------------------------------------------------
__global__ __launch_bounds__(256) void packgate_kernel(
    const float* __restrict__ dsw, const float* __restrict__ dtw,
    half_t* __restrict__ Wg)
{
    const int idx = blockIdx.x * 256 + threadIdx.x;     // 30*1024*64
    const int kg = idx & 63;
    const int r = (idx >> 6) & 1023;
    const int l = idx >> 16;
    const int rsub = r & 63;
    const int c = (r >> 6) * 32 + (rsub & 31);
    const float* src = (rsub < 32) ? dsw : dtw;
    const int k0 = kg * 8;
    const float4* p = (const float4*)(src + (((size_t)l * 512 + c) * 512 + k0) * 2);
    const float4 q0 = p[0], q1 = p[1], q2 = p[2], q3 = p[3];
    f16x8 cur = {f2h(q0.y), f2h(q0.w), f2h(q1.y), f2h(q1.w),
                 f2h(q2.y), f2h(q2.w), f2h(q3.y), f2h(q3.w)};
    f16x8 pst = {f2h(q0.x), f2h(q0.z), f2h(q1.x), f2h(q1.z),
                 f2h(q2.x), f2h(q2.z), f2h(q3.x), f2h(q3.z)};
    half_t* row = Wg + ((size_t)l * 1024 + r) * 1088;
    *(f16x8*)&row[k0] = cur;
    *(f16x8*)&row[512 + k0] = pst;
}

// aux cols [1024,1088) of Wg
__global__ __launch_bounds__(256) void packgaux_kernel(
    const float* __restrict__ asw, const float* __restrict__ atw,
    half_t* __restrict__ Wg)
{
    const int idx = blockIdx.x * 256 + threadIdx.x;     // 30*1024*8
    const int j8 = idx & 7;
    const int r = (idx >> 3) & 1023;
    const int l = idx >> 13;
    const int rsub = r & 63;
    const int c = (r >> 6) * 32 + (rsub & 31);
    const float* src = (rsub < 32) ? asw : atw;
    f16x8 v = {};
#pragma unroll
    for (int e = 0; e < 8; e++) {
        const int j = j8 * 8 + e;
        if (j < NAUX_) v[e] = f2h(src[((size_t)l * 512 + c) * NAUX_ + j]);
    }
    *(f16x8*)&Wg[((size_t)l * 1024 + r) * 1088 + 1024 + j8 * 8] = v;
}

__global__ __launch_bounds__(256) void packsr_kernel(
    const float* __restrict__ rsw, const float* __restrict__ skw,
    half_t* __restrict__ Wsr)
{
    const int idx = blockIdx.x * 256 + threadIdx.x;     // 30*768*128
    const int c = (idx & 127) * 4;
    const int r = (idx >> 7) % 768;
    const int l = idx / (128 * 768);
    const float4 v = (r < 512)
        ? *(const float4*)&rsw[((size_t)l * 512 + r) * 512 + c]
        : *(const float4*)&skw[((size_t)l * 256 + (r - 512)) * 512 + c];
    f16x4 o = {f2h(v.x), f2h(v.y), f2h(v.z), f2h(v.w)};
    *(f16x4*)(Wsr + ((size_t)l * 768 + r) * 512 + c) = o;
}

__global__ __launch_bounds__(256) void packpost_kernel(
    const float* __restrict__ p1w, const float* __restrict__ p2w,
    const float* __restrict__ lw, half_t* __restrict__ Wpost)
{
    const int idx = blockIdx.x * 256 + threadIdx.x;     // 3*256*64
    const int c = (idx & 63) * 4;
    const int r = (idx >> 6) & 255;
    const int mi = idx >> 14;
    const float* src = (mi == 0) ? p1w : (mi == 1) ? p2w : lw;
    const float4 v = *(const float4*)&src[(size_t)r * 256 + c];
    f16x4 o = {f2h(v.x), f2h(v.y), f2h(v.z), f2h(v.w)};
    *(f16x4*)(Wpost + (size_t)mi * 65536 + (size_t)r * 256 + c) = o;
}

// biasG rows follow Wg row mapping; biasSr unchanged
__global__ __launch_bounds__(256) void packbias_kernel(
    const float* __restrict__ dsb, const float* __restrict__ asb,
    const float* __restrict__ dtb, const float* __restrict__ atb,
    const float* __restrict__ rsb, const float* __restrict__ skb,
    float* __restrict__ biasG, float* __restrict__ biasSr)
{
    const int idx = blockIdx.x * 256 + threadIdx.x;
    if (idx < 30 * 1024) {
        const int l = idx >> 10, r = idx & 1023;
        const int rsub = r & 63;
        const int c = (r >> 6) * 32 + (rsub & 31);
        const float v = (rsub < 32) ? (dsb[l * 512 + c] + asb[l * 512 + c])
                                    : (dtb[l * 512 + c] + atb[l * 512 + c]);
        biasG[idx] = v;
    } else if (idx < 30 * 1024 + 30 * 768) {
        const int j = idx - 30 * 1024;
        const int l = j / 768, r = j % 768;
        biasSr[j] = (r < 512) ? rsb[l * 512 + r] : skb[l * 256 + (r - 512)];
    }
}

// ---------------------------------------------------------------------------
extern "C" void kernel_launch(void* const* d_in, const int* in_sizes, int n_in,
                              void* d_out, int out_size, void* d_ws, size_t ws_size,
                              hipStream_t stream)
{
    (void)in_sizes; (void)n_in; (void)out_size; (void)ws_size;

    const int* x = (const int*)d_in[0];
    const float* h = (const float*)d_in[1];
    const float* causal_w = (const float*)d_in[2];
    const float* causal_b = (const float*)d_in[3];
    const float* dsw = (const float*)d_in[4];
    const float* dsb = (const float*)d_in[5];
    const float* dtw = (const float*)d_in[6];
    const float* dtb = (const float*)d_in[7];
    const float* asw = (const float*)d_in[8];
    const float* asb = (const float*)d_in[9];
    const float* atw = (const float*)d_in[10];
    const float* atb = (const float*)d_in[11];
    const float* skw = (const float*)d_in[12];
    const float* skb = (const float*)d_in[13];
    const float* rsw = (const float*)d_in[14];
    const float* rsb = (const float*)d_in[15];
    const float* p1w = (const float*)d_in[16];
    const float* p1b = (const float*)d_in[17];
    const float* p2w = (const float*)d_in[18];
    const float* p2b = (const float*)d_in[19];
    const float* lw  = (const float*)d_in[20];
    const float* lb  = (const float*)d_in[21];

    char* ws = (char*)d_ws;
    size_t off = 0;
    auto alloc = [&](size_t bytes) { char* p = ws + off; off += (bytes + 255) & ~(size_t)255; return p; };

    half_t* Wg     = (half_t*)alloc((size_t)L_ * 1024 * 1088 * 2);
    half_t* Wsr    = (half_t*)alloc((size_t)L_ * 768 * 512 * 2);
    half_t* Wpost  = (half_t*)alloc((size_t)3 * 256 * 256 * 2);
    float*  biasG  = (float*) alloc((size_t)L_ * 1024 * 4);
    float*  biasSr = (float*) alloc((size_t)L_ * 768 * 4);
    half_t* actB   = (half_t*)alloc((size_t)B_ * T_ * 576 * 2);
    half_t* g      = (half_t*)alloc((size_t)B_ * T_ * 512 * 2);
    half_t* skipH  = (half_t*)alloc((size_t)B_ * T_ * 256 * 2);
    half_t* zbuf   = (half_t*)alloc(256);
    half_t* pA     = (half_t*)alloc((size_t)B_ * T_ * 256 * 2);
    half_t* pB     = (half_t*)alloc((size_t)B_ * T_ * 256 * 2);

    // zero skipH + zbuf (adjacent, skipH size is 256-aligned)
    hipMemsetAsync(skipH, 0, (size_t)B_ * T_ * 256 * 2 + 256, stream);

    packgate_kernel<<<30 * 1024 * 64 / 256, 256, 0, stream>>>(dsw, dtw, Wg);
    packgaux_kernel<<<30 * 1024 * 8 / 256, 256, 0, stream>>>(asw, atw, Wg);
    packsr_kernel<<<30 * 768 * 128 / 256, 256, 0, stream>>>(rsw, skw, Wsr);
    packpost_kernel<<<3 * 256 * 64 / 256, 256, 0, stream>>>(p1w, p2w, lw, Wpost);
    packbias_kernel<<<(30 * 1024 + 30 * 768 + 255) / 256, 256, 0, stream>>>(
        dsb, asb, dtb, atb, rsb, skb, biasG, biasSr);
    packh_kernel<<<B_ * T_ * 64 / 256, 256, 0, stream>>>(h, actB);
    embed_kernel<<<dim3(T_, B_), 256, 0, stream>>>(x, causal_w, causal_b, actB);

    for (int l = 0; l < L_; l++) {
        const int dil = 1 << (l % 10);
        gates_gemm<<<dim3(32, 8, B_), 256, 0, stream>>>(
            actB, Wg + (size_t)l * 1024 * 1088, biasG + (size_t)l * 1024, g, zbuf, dil);
        gemm_mfma<3><<<dim3(32, 6, B_), 256, 0, stream>>>(
            g, Wsr + (size_t)l * 768 * 512, biasSr + (size_t)l * 768, nullptr, 768, 512,
            actB, skipH);
    }

    relupack_kernel<<<B_ * T_ * 64 / 256, 256, 0, stream>>>(skipH, pA);
    gemm_mfma<1><<<dim3(32, 2, B_), 256, 0, stream>>>(pA, Wpost, p1b, pB, 256, 256,
                                                      nullptr, nullptr);
    gemm_mfma<0><<<dim3(32, 2, B_), 256, 0, stream>>>(pB, Wpost + 65536, p2b, pA, 256, 256,
                                                      nullptr, nullptr);
    gemm_mfma<2><<<dim3(32, 2, B_), 256, 0, stream>>>(pA, Wpost + 131072, lb, d_out, 256, 256,
                                                      nullptr, nullptr);
}

// Round 7
// 1524.460 us; speedup vs baseline: 11.7702x; 1.0170x over previous
//
#include <hip/hip_runtime.h>
#include <cstddef>

#define B_ 2
#define T_ 4096
#define NQ_ 256
#define NAUX_ 28
#define NR_ 512
#define NS_ 256
#define L_ 30

typedef _Float16 half_t;
typedef __attribute__((ext_vector_type(8))) _Float16 f16x8;
typedef __attribute__((ext_vector_type(4))) _Float16 f16x4;
typedef __attribute__((ext_vector_type(4))) float f32x4;

__device__ inline half_t f2h(float f) { return (half_t)f; }
__device__ inline float h2f(half_t h) { return (float)h; }

// async global->LDS, 16 B per lane; LDS dest = wave base + lane*16
__device__ __forceinline__ void gload16(const void* g, void* l) {
    __builtin_amdgcn_global_load_lds(
        (const __attribute__((address_space(1))) unsigned int*)g,
        (__attribute__((address_space(3))) unsigned int*)l, 16, 0, 0);
}

// ---------------------------------------------------------------------------
// Weight fragment-blob layout: for M x K weights, blob(mg, ks) holds the
// 16-row x 32-col MFMA A-fragment for m in [mg*16,mg*16+16), k in [ks*32,+32):
// 64 lanes x 8 halves contiguous; lane l -> row mg*16+(l&15), k ks*32+(l>>4)*8.
// Flat half offset: (mg*NKS + ks)*512 + lane*8, NKS = K/32.
// ---------------------------------------------------------------------------

// ---------------------------------------------------------------------------
// Fused gates GEMM + gating (A-direct, B-LDS-dbuf, 1 barrier/chunk).
// M=1024 rows: group gidx=r>>6, rsub=r&63; rsub<32 -> sig ch gidx*32+rsub,
// else tanh ch gidx*32+rsub-32. K=1088: [0,512)=cur, [512,1024)=past,
// [1024,1088)=aux. grid (32, 8, B), 256 threads.
// ---------------------------------------------------------------------------
__global__ __launch_bounds__(256, 2) void gates_gemm(
    const half_t* __restrict__ actB, const half_t* __restrict__ Wf,
    const float* __restrict__ biasG, half_t* __restrict__ g,
    const half_t* __restrict__ zbuf, int dil)
{
    __shared__ __align__(16) half_t sB[2][128 * 64];

    const int tid = threadIdx.x;
    const int b = blockIdx.z;
    const int tB = blockIdx.x * 128;
    const int w = tid >> 6, lane = tid & 63;
    const int wm = w >> 1, wn = w & 1;
    const int l15 = lane & 15, lg = lane >> 4;
    const int rr = lane >> 3, cc = lane & 7;
    const int sc8 = cc ^ rr;

    f32x4 acc[4][4] = {};
    f16x8 a0[8], a1[8];

    const int mgW = blockIdx.y * 8 + wm * 4;   // blob m-group base for this wave

    auto loadA = [&](f16x8* d, int kc) {
#pragma unroll
        for (int i = 0; i < 4; i++)
#pragma unroll
            for (int s = 0; s < 2; s++)
                d[i * 2 + s] = *(const f16x8*)&Wf[((size_t)(mgW + i) * 34 + kc * 2 + s) * 512 + lane * 8];
    };
    auto stageB = [&](int kc, int buf) {
#pragma unroll
        for (int it = 0; it < 4; it++) {
            const int t = tB + w * 32 + it * 8 + rr;
            const half_t* p;
            if (kc < 8) {
                p = actB + ((size_t)b * T_ + t) * 576 + kc * 64;
            } else if (kc < 16) {
                const int tp = t - dil;
                p = (tp >= 0) ? actB + ((size_t)b * T_ + tp) * 576 + (kc - 8) * 64
                              : zbuf;
            } else {
                p = actB + ((size_t)b * T_ + t) * 576 + 512;
            }
            gload16(p + sc8 * 8, &sB[buf][(w * 32 + it * 8) * 64]);
        }
    };
    auto compute = [&](const f16x8* a, int buf) {
#pragma unroll
        for (int s = 0; s < 2; s++) {
            f16x8 bv[4];
#pragma unroll
            for (int j = 0; j < 4; j++) {
                const int r = wn * 64 + j * 16 + l15;
                bv[j] = *(const f16x8*)&sB[buf][r * 64 + (((s * 4 + lg) ^ (l15 & 7)) * 8)];
            }
#pragma unroll
            for (int i = 0; i < 4; i++)
#pragma unroll
                for (int j = 0; j < 4; j++)
                    acc[i][j] = __builtin_amdgcn_mfma_f32_16x16x32_f16(a[i * 2 + s], bv[j], acc[i][j], 0, 0, 0);
        }
    };

    stageB(0, 0);
    loadA(a0, 0);
#pragma unroll
    for (int kc = 0; kc < 17; kc++) {
        __syncthreads();
        if (kc + 1 < 17) {
            stageB(kc + 1, (kc + 1) & 1);
            loadA((kc & 1) ? a0 : a1, kc + 1);
        }
        compute((kc & 1) ? a1 : a0, kc & 1);
    }

    const int gidx = blockIdx.y * 2 + wm;
    const int t0 = tB + wn * 64 + l15;
#pragma unroll
    for (int i = 0; i < 2; i++) {
        const int c = gidx * 32 + i * 16 + lg * 4;
        const float4 bs = *(const float4*)&biasG[gidx * 64 + i * 16 + lg * 4];
        const float4 bt4 = *(const float4*)&biasG[gidx * 64 + 32 + i * 16 + lg * 4];
        const float bsa[4] = {bs.x, bs.y, bs.z, bs.w};
        const float bta[4] = {bt4.x, bt4.y, bt4.z, bt4.w};
#pragma unroll
        for (int j = 0; j < 4; j++) {
            const int t = t0 + j * 16;
            f16x4 o;
#pragma unroll
            for (int e = 0; e < 4; e++) {
                const float sv = acc[i][j][e] + bsa[e];
                const float tv = acc[i + 2][j][e] + bta[e];
                const float sg = 1.f / (1.f + __expf(-sv));
                const float ex = __expf(-2.f * tv);
                const float th = (1.f - ex) / (1.f + ex);
                o[e] = f2h(sg * th);
            }
            *(f16x4*)(g + ((size_t)b * T_ + t) * 512 + c) = o;
        }
    }
}

// ---------------------------------------------------------------------------
// Generic GEMM (A-direct blob weights, B-LDS-dbuf, 1 barrier/chunk).
// K compile-time (512 or 256). EPI: 0 fp16, 1 fp16+relu, 2 f32,
// 3 fused res/skip fp16 RMW (m<512 actB, m>=512 skipH).
// ---------------------------------------------------------------------------
template<int K, int EPI>
__global__ __launch_bounds__(256, 2) void gemm_mfma(
    const half_t* __restrict__ X, const half_t* __restrict__ Wf,
    const float* __restrict__ bias, void* __restrict__ out, int M,
    half_t* __restrict__ actB, half_t* __restrict__ skipH)
{
    constexpr int NK = K / 64;
    constexpr int NKS = K / 32;
    __shared__ __align__(16) half_t sB[2][128 * 64];

    const int tid = threadIdx.x;
    const int b = blockIdx.z;
    const int tB = blockIdx.x * 128;
    const int mB = blockIdx.y * 128;
    const int w = tid >> 6, lane = tid & 63;
    const int wm = w >> 1, wn = w & 1;
    const int l15 = lane & 15, lg = lane >> 4;
    const int rr = lane >> 3, cc = lane & 7;
    const int sc8 = cc ^ rr;

    f32x4 acc[4][4] = {};
    f16x8 a0[8], a1[8];

    const int mgW = (mB >> 4) + wm * 4;
    const half_t* Xb = X + ((size_t)b * T_ + tB) * K;

    auto loadA = [&](f16x8* d, int kc) {
#pragma unroll
        for (int i = 0; i < 4; i++)
#pragma unroll
            for (int s = 0; s < 2; s++)
                d[i * 2 + s] = *(const f16x8*)&Wf[((size_t)(mgW + i) * NKS + kc * 2 + s) * 512 + lane * 8];
    };
    auto stageB = [&](int kc, int buf) {
#pragma unroll
        for (int it = 0; it < 4; it++) {
            const int row = w * 32 + it * 8;
            gload16(Xb + (size_t)(row + rr) * K + kc * 64 + sc8 * 8,
                    &sB[buf][row * 64]);
        }
    };
    auto compute = [&](const f16x8* a, int buf) {
#pragma unroll
        for (int s = 0; s < 2; s++) {
            f16x8 bv[4];
#pragma unroll
            for (int j = 0; j < 4; j++) {
                const int r = wn * 64 + j * 16 + l15;
                bv[j] = *(const f16x8*)&sB[buf][r * 64 + (((s * 4 + lg) ^ (l15 & 7)) * 8)];
            }
#pragma unroll
            for (int i = 0; i < 4; i++)
#pragma unroll
                for (int j = 0; j < 4; j++)
                    acc[i][j] = __builtin_amdgcn_mfma_f32_16x16x32_f16(a[i * 2 + s], bv[j], acc[i][j], 0, 0, 0);
        }
    };

    stageB(0, 0);
    loadA(a0, 0);
#pragma unroll
    for (int kc = 0; kc < NK; kc++) {
        __syncthreads();
        if (kc + 1 < NK) {
            stageB(kc + 1, (kc + 1) & 1);
            loadA((kc & 1) ? a0 : a1, kc + 1);
        }
        compute((kc & 1) ? a1 : a0, kc & 1);
    }

    const int n0 = tB + wn * 64 + l15;
#pragma unroll
    for (int i = 0; i < 4; i++) {
        const int m = mB + wm * 64 + i * 16 + lg * 4;
        float4 bv = make_float4(0.f, 0.f, 0.f, 0.f);
        if (bias) bv = *(const float4*)&bias[m];
#pragma unroll
        for (int j = 0; j < 4; j++) {
            const int t = n0 + j * 16;
            float o0 = acc[i][j][0] + bv.x, o1 = acc[i][j][1] + bv.y;
            float o2 = acc[i][j][2] + bv.z, o3 = acc[i][j][3] + bv.w;
            if (EPI == 1) {
                o0 = fmaxf(o0, 0.f); o1 = fmaxf(o1, 0.f);
                o2 = fmaxf(o2, 0.f); o3 = fmaxf(o3, 0.f);
            }
            if (EPI == 3) {
                const size_t bt = (size_t)b * T_ + t;
                half_t* p = (mB < 512) ? (actB + bt * 576 + m)
                                       : (skipH + bt * 256 + (m - 512));
                f16x4 old = *(const f16x4*)p;
                f16x4 nv = {f2h(h2f(old.x) + o0), f2h(h2f(old.y) + o1),
                            f2h(h2f(old.z) + o2), f2h(h2f(old.w) + o3)};
                *(f16x4*)p = nv;
            } else {
                const size_t off = ((size_t)b * T_ + t) * M + m;
                if (EPI == 2) {
                    *(float4*)((float*)out + off) = make_float4(o0, o1, o2, o3);
                } else {
                    f16x4 ov = {f2h(o0), f2h(o1), f2h(o2), f2h(o3)};
                    *(f16x4*)((half_t*)out + off) = ov;
                }
            }
        }
    }
}

// relu(skipH) -> fp16 dense
__global__ __launch_bounds__(256) void relupack_kernel(
    const half_t* __restrict__ skipH, half_t* __restrict__ outp)
{
    const int idx = blockIdx.x * 256 + threadIdx.x;     // 8192*64
    const int c = (idx & 63) * 4;
    const int bt = idx >> 6;
    const f16x4 v = *(const f16x4*)(skipH + (size_t)bt * 256 + c);
    f16x4 o = {f2h(fmaxf(h2f(v.x), 0.f)), f2h(fmaxf(h2f(v.y), 0.f)),
               f2h(fmaxf(h2f(v.z), 0.f)), f2h(fmaxf(h2f(v.w), 0.f))};
    *(f16x4*)(outp + (size_t)bt * 256 + c) = o;
}

// ---------------------------------------------------------------------------
// Embed: actB[t][c] = fp16(cw[c][x[t]][1] + cw[c][x[t-1]][0] + cb[c])
// ---------------------------------------------------------------------------
__global__ __launch_bounds__(256) void embed_kernel(
    const int* __restrict__ x, const float* __restrict__ cw,
    const float* __restrict__ cb, half_t* __restrict__ actB)
{
    const int t = blockIdx.x, b = blockIdx.y;
    const int idc = x[b * T_ + t];
    const int idp = (t > 0) ? x[b * T_ + t - 1] : -1;
    const size_t bt = (size_t)b * T_ + t;
    for (int c = threadIdx.x; c < 512; c += 256) {
        float v = cw[(c * 256 + idc) * 2 + 1] + cb[c];
        if (idp >= 0) v += cw[(c * 256 + idp) * 2 + 0];
        actB[bt * 576 + c] = f2h(v);
    }
}

// aux channels: actB[t][512+j] = fp16(h[b][j][t]) for j<28 else 0
__global__ __launch_bounds__(256) void packh_kernel(
    const float* __restrict__ h, half_t* __restrict__ actB)
{
    const int idx = blockIdx.x * 256 + threadIdx.x;     // 8192*64
    const int j = idx & 63;
    const int bt = idx >> 6;
    const int b = bt >> 12, t = bt & 4095;
    const float v = (j < 28) ? h[((size_t)b * NAUX_ + j) * T_ + t] : 0.f;
    actB[(size_t)bt * 576 + 512 + j] = f2h(v);
}

// ---------------------------------------------------------------------------
// Pack gate weights into blob layout. Wg per layer = 64 mg x 34 ks x 512 h.
// Thread -> (l, mg, ks<16, lane): reads 16 floats (8 k x 2 taps), writes
// cur blob slot (ks) and past blob slot (16+ks), 16 B per store,
// wave-contiguous 1 KB.
// ---------------------------------------------------------------------------
__global__ __launch_bounds__(256) void packgate_kernel(
    const float* __restrict__ dsw, const float* __restrict__ dtw,
    half_t* __restrict__ Wg)
{
    const int idx = blockIdx.x * 256 + threadIdx.x;     // 30*64*16*64
    const int lane = idx & 63;
    const int ks = (idx >> 6) & 15;
    const int mg = (idx >> 10) & 63;
    const int l = idx >> 16;
    const int r = mg * 16 + (lane & 15);
    const int rsub = r & 63;
    const int c = (r >> 6) * 32 + (rsub & 31);
    const float* src = (rsub < 32) ? dsw : dtw;
    const size_t base = ((size_t)(l * 512 + c) * 512 + ks * 32 + (lane >> 4) * 8) * 2;
    const float4* p = (const float4*)(src + base);
    const float4 q0 = p[0], q1 = p[1], q2 = p[2], q3 = p[3];
    f16x8 cur = {f2h(q0.y), f2h(q0.w), f2h(q1.y), f2h(q1.w),
                 f2h(q2.y), f2h(q2.w), f2h(q3.y), f2h(q3.w)};
    f16x8 pst = {f2h(q0.x), f2h(q0.z), f2h(q1.x), f2h(q1.z),
                 f2h(q2.x), f2h(q2.z), f2h(q3.x), f2h(q3.z)};
    half_t* dst = Wg + (size_t)l * 1114112;
    *(f16x8*)&dst[((size_t)(mg * 34 + ks) * 64 + lane) * 8] = cur;
    *(f16x8*)&dst[((size_t)(mg * 34 + 16 + ks) * 64 + lane) * 8] = pst;
}

// aux blob slots ks=32,33 of Wg
__global__ __launch_bounds__(256) void packgaux_kernel(
    const float* __restrict__ asw, const float* __restrict__ atw,
    half_t* __restrict__ Wg)
{
    const int idx = blockIdx.x * 256 + threadIdx.x;     // 30*64*2*64
    const int lane = idx & 63;
    const int ksd = (idx >> 6) & 1;
    const int mg = (idx >> 7) & 63;
    const int l = idx >> 13;
    const int r = mg * 16 + (lane & 15);
    const int rsub = r & 63;
    const int c = (r >> 6) * 32 + (rsub & 31);
    const float* src = (rsub < 32) ? asw : atw;
    const int j0 = ksd * 32 + (lane >> 4) * 8;
    f16x8 v = {};
#pragma unroll
    for (int e = 0; e < 8; e++) {
        const int j = j0 + e;
        if (j < NAUX_) v[e] = f2h(src[(size_t)(l * 512 + c) * NAUX_ + j]);
    }
    Wg += (size_t)l * 1114112;
    *(f16x8*)&Wg[((size_t)(mg * 34 + 32 + ksd) * 64 + lane) * 8] = v;
}

// sr weights blob: 48 mg x 16 ks x 512 h per layer
__global__ __launch_bounds__(256) void packsr_kernel(
    const float* __restrict__ rsw, const float* __restrict__ skw,
    half_t* __restrict__ Wsr)
{
    const int idx = blockIdx.x * 256 + threadIdx.x;     // 30*48*16*64
    const int lane = idx & 63;
    const int ks = (idx >> 6) & 15;
    const int mg = (idx >> 10) % 48;
    const int l = (idx >> 10) / 48;
    const int r = mg * 16 + (lane & 15);
    const int kb = ks * 32 + (lane >> 4) * 8;
    const float* src = (r < 512) ? (rsw + ((size_t)l * 512 + r) * 512 + kb)
                                 : (skw + ((size_t)l * 256 + (r - 512)) * 512 + kb);
    const float4 q0 = ((const float4*)src)[0], q1 = ((const float4*)src)[1];
    f16x8 v = {f2h(q0.x), f2h(q0.y), f2h(q0.z), f2h(q0.w),
               f2h(q1.x), f2h(q1.y), f2h(q1.z), f2h(q1.w)};
    *(f16x8*)&Wsr[(size_t)l * 393216 + ((size_t)(mg * 16 + ks) * 64 + lane) * 8] = v;
}

// post weights blob: 16 mg x 8 ks x 512 h per matrix
__global__ __launch_bounds__(256) void packpost_kernel(
    const float* __restrict__ p1w, const float* __restrict__ p2w,
    const float* __restrict__ lw, half_t* __restrict__ Wpost)
{
    const int idx = blockIdx.x * 256 + threadIdx.x;     // 3*16*8*64
    const int lane = idx & 63;
    const int ks = (idx >> 6) & 7;
    const int mg = (idx >> 9) & 15;
    const int mi = idx >> 13;
    const float* src = (mi == 0) ? p1w : (mi == 1) ? p2w : lw;
    const int r = mg * 16 + (lane & 15);
    const int kb = ks * 32 + (lane >> 4) * 8;
    const float4 q0 = ((const float4*)(src + (size_t)r * 256 + kb))[0];
    const float4 q1 = ((const float4*)(src + (size_t)r * 256 + kb))[1];
    f16x8 v = {f2h(q0.x), f2h(q0.y), f2h(q0.z), f2h(q0.w),
               f2h(q1.x), f2h(q1.y), f2h(q1.z), f2h(q1.w)};
    *(f16x8*)&Wpost[(size_t)mi * 65536 + ((size_t)(mg * 8 + ks) * 64 + lane) * 8] = v;
}

// biasG rows follow gate row mapping; biasSr plain
__global__ __launch_bounds__(256) void packbias_kernel(
    const float* __restrict__ dsb, const float* __restrict__ asb,
    const float* __restrict__ dtb, const float* __restrict__ atb,
    const float* __restrict__ rsb, const float* __restrict__ skb,
    float* __restrict__ biasG, float* __restrict__ biasSr)
{
    const int idx = blockIdx.x * 256 + threadIdx.x;
    if (idx < 30 * 1024) {
        const int l = idx >> 10, r = idx & 1023;
        const int rsub = r & 63;
        const int c = (r >> 6) * 32 + (rsub & 31);
        const float v = (rsub < 32) ? (dsb[l * 512 + c] + asb[l * 512 + c])
                                    : (dtb[l * 512 + c] + atb[l * 512 + c]);
        biasG[idx] = v;
    } else if (idx < 30 * 1024 + 30 * 768) {
        const int j = idx - 30 * 1024;
        const int l = j / 768, r = j % 768;
        biasSr[j] = (r < 512) ? rsb[l * 512 + r] : skb[l * 256 + (r - 512)];
    }
}

// ---------------------------------------------------------------------------
extern "C" void kernel_launch(void* const* d_in, const int* in_sizes, int n_in,
                              void* d_out, int out_size, void* d_ws, size_t ws_size,
                              hipStream_t stream)
{
    (void)in_sizes; (void)n_in; (void)out_size; (void)ws_size;

    const int* x = (const int*)d_in[0];
    const float* h = (const float*)d_in[1];
    const float* causal_w = (const float*)d_in[2];
    const float* causal_b = (const float*)d_in[3];
    const float* dsw = (const float*)d_in[4];
    const float* dsb = (const float*)d_in[5];
    const float* dtw = (const float*)d_in[6];
    const float* dtb = (const float*)d_in[7];
    const float* asw = (const float*)d_in[8];
    const float* asb = (const float*)d_in[9];
    const float* atw = (const float*)d_in[10];
    const float* atb = (const float*)d_in[11];
    const float* skw = (const float*)d_in[12];
    const float* skb = (const float*)d_in[13];
    const float* rsw = (const float*)d_in[14];
    const float* rsb = (const float*)d_in[15];
    const float* p1w = (const float*)d_in[16];
    const float* p1b = (const float*)d_in[17];
    const float* p2w = (const float*)d_in[18];
    const float* p2b = (const float*)d_in[19];
    const float* lw  = (const float*)d_in[20];
    const float* lb  = (const float*)d_in[21];

    char* ws = (char*)d_ws;
    size_t off = 0;
    auto alloc = [&](size_t bytes) { char* p = ws + off; off += (bytes + 255) & ~(size_t)255; return p; };

    half_t* Wg     = (half_t*)alloc((size_t)L_ * 1114112 * 2);
    half_t* Wsr    = (half_t*)alloc((size_t)L_ * 393216 * 2);
    half_t* Wpost  = (half_t*)alloc((size_t)3 * 65536 * 2);
    float*  biasG  = (float*) alloc((size_t)L_ * 1024 * 4);
    float*  biasSr = (float*) alloc((size_t)L_ * 768 * 4);
    half_t* actB   = (half_t*)alloc((size_t)B_ * T_ * 576 * 2);
    half_t* g      = (half_t*)alloc((size_t)B_ * T_ * 512 * 2);
    half_t* skipH  = (half_t*)alloc((size_t)B_ * T_ * 256 * 2);
    half_t* zbuf   = (half_t*)alloc(256);
    half_t* pA     = (half_t*)alloc((size_t)B_ * T_ * 256 * 2);
    half_t* pB     = (half_t*)alloc((size_t)B_ * T_ * 256 * 2);

    // zero skipH + zbuf (adjacent)
    hipMemsetAsync(skipH, 0, (size_t)B_ * T_ * 256 * 2 + 256, stream);

    packgate_kernel<<<30 * 64 * 16 * 64 / 256, 256, 0, stream>>>(dsw, dtw, Wg);
    packgaux_kernel<<<30 * 64 * 2 * 64 / 256, 256, 0, stream>>>(asw, atw, Wg);
    packsr_kernel<<<30 * 48 * 16 * 64 / 256, 256, 0, stream>>>(rsw, skw, Wsr);
    packpost_kernel<<<3 * 16 * 8 * 64 / 256, 256, 0, stream>>>(p1w, p2w, lw, Wpost);
    packbias_kernel<<<(30 * 1024 + 30 * 768 + 255) / 256, 256, 0, stream>>>(
        dsb, asb, dtb, atb, rsb, skb, biasG, biasSr);
    packh_kernel<<<B_ * T_ * 64 / 256, 256, 0, stream>>>(h, actB);
    embed_kernel<<<dim3(T_, B_), 256, 0, stream>>>(x, causal_w, causal_b, actB);

    for (int l = 0; l < L_; l++) {
        const int dil = 1 << (l % 10);
        gates_gemm<<<dim3(32, 8, B_), 256, 0, stream>>>(
            actB, Wg + (size_t)l * 1114112, biasG + (size_t)l * 1024, g, zbuf, dil);
        gemm_mfma<512, 3><<<dim3(32, 6, B_), 256, 0, stream>>>(
            g, Wsr + (size_t)l * 393216, biasSr + (size_t)l * 768, nullptr, 768,
            actB, skipH);
    }

    relupack_kernel<<<B_ * T_ * 64 / 256, 256, 0, stream>>>(skipH, pA);
    gemm_mfma<256, 1><<<dim3(32, 2, B_), 256, 0, stream>>>(pA, Wpost, p1b, pB, 256,
                                                           nullptr, nullptr);
    gemm_mfma<256, 0><<<dim3(32, 2, B_), 256, 0, stream>>>(pB, Wpost + 65536, p2b, pA, 256,
                                                           nullptr, nullptr);
    gemm_mfma<256, 2><<<dim3(32, 2, B_), 256, 0, stream>>>(pA, Wpost + 131072, lb, d_out, 256,
                                                           nullptr, nullptr);
}